// Round 7
// baseline (135.694 us; speedup 1.0000x reference)
//
#include <hip/hip_runtime.h>
#include <hip/hip_bf16.h>
#include <cstdint>
#include <cmath>

#define SEQ 2048
#define NH 16
#define DM 1024
#define BATCH 2

typedef short bf16x8 __attribute__((ext_vector_type(8)));
typedef float f32x4 __attribute__((ext_vector_type(4)));
typedef const void __attribute__((address_space(1)))* gas_t;
typedef void __attribute__((address_space(3)))* las_t;

#if __has_builtin(__builtin_amdgcn_exp2f)
#define EXP2(x) __builtin_amdgcn_exp2f(x)
#else
#define EXP2(x) __expf((x) * 0.6931471805599453f)
#endif

// Q prescale: (1/sqrt(64)) * log2(e) so scores are already in log2 domain
#define QSCALE 0.18033688011112042f

static __device__ __forceinline__ unsigned short f2bf(float f) {
    union { __hip_bfloat16 h; unsigned short u; } cv;
    cv.h = __float2bfloat16(f);
    return cv.u;
}
static __device__ __forceinline__ float bf2f(unsigned short u) {
    union { unsigned short u; __hip_bfloat16 h; } cv;
    cv.u = u;
    return __bfloat162float(cv.h);
}
static __device__ __forceinline__ unsigned packbf(float lo, float hi) {
    return (unsigned)f2bf(lo) | ((unsigned)f2bf(hi) << 16);
}

static __device__ __forceinline__ void gload_lds16(const void* g, void* l) {
    __builtin_amdgcn_global_load_lds(
        reinterpret_cast<gas_t>(reinterpret_cast<uintptr_t>(g)),
        reinterpret_cast<las_t>(reinterpret_cast<uintptr_t>(l)),
        16, 0, 0);
}

// ---------------- fp32 -> bf16 convert, all 5 tensors in one launch ----------
__global__ __launch_bounds__(256) void cvt_all(
    const float* __restrict__ x,  const float* __restrict__ wq,
    const float* __restrict__ wk, const float* __restrict__ wv,
    const float* __restrict__ wo,
    unsigned short* __restrict__ xb, unsigned short* __restrict__ wqkv,
    unsigned short* __restrict__ wob) {
    int blk = blockIdx.x;
    const float* src; unsigned short* dst; int base;
    if (blk < 4096)      { src = x;  dst = xb;              base = blk; }
    else if (blk < 5120) { src = wq; dst = wqkv;            base = blk - 4096; }
    else if (blk < 6144) { src = wk; dst = wqkv + 1048576;  base = blk - 5120; }
    else if (blk < 7168) { src = wv; dst = wqkv + 2097152;  base = blk - 6144; }
    else                 { src = wo; dst = wob;             base = blk - 7168; }
    int i = base * 256 + threadIdx.x;
    float4 v = reinterpret_cast<const float4*>(src)[i];
    ushort4 o;
    o.x = f2bf(v.x); o.y = f2bf(v.y); o.z = f2bf(v.z); o.w = f2bf(v.w);
    reinterpret_cast<ushort4*>(dst)[i] = o;
}

// ---------------- bf16 GEMM: C[M][N] = A[M][K] * B[N][K]^T ----------------
template<int OUT_BF16>
__global__ __launch_bounds__(256) void gemm_bt(
    const unsigned short* __restrict__ A,
    const unsigned short* __restrict__ B,
    void* __restrict__ C, int M, int N, int K) {
    __shared__ unsigned short As[128 * 32];
    __shared__ unsigned short Bs[128 * 32];
    const int tid = threadIdx.x;
    const int lane = tid & 63, wid = tid >> 6;
    const int wr = wid >> 1, wc = wid & 1;
    const int ln15 = lane & 15, kq = lane >> 4;
    const int bm = blockIdx.y, bn = blockIdx.x;

    f32x4 acc[4][4] = {};
    const int nk = K >> 5;
    for (int kt = 0; kt < nk; ++kt) {
        #pragma unroll
        for (int i = 0; i < 2; ++i) {
            int c = i * 256 + tid;
            int row = c >> 2, k8 = (c & 3) << 3;
            size_t gofsA = (size_t)(bm * 128 + row) * K + kt * 32 + k8;
            size_t gofsB = (size_t)(bn * 128 + row) * K + kt * 32 + k8;
            unsigned ldsoff = (unsigned)(i * 256 + wid * 64) * 16;  // wave-uniform
            gload_lds16(A + gofsA, (char*)As + ldsoff);
            gload_lds16(B + gofsB, (char*)Bs + ldsoff);
        }
        __syncthreads();
        bf16x8 af[4], bf[4];
        #pragma unroll
        for (int m = 0; m < 4; ++m)
            af[m] = *reinterpret_cast<const bf16x8*>(&As[(wr * 64 + m * 16 + ln15) * 32 + kq * 8]);
        #pragma unroll
        for (int n = 0; n < 4; ++n)
            bf[n] = *reinterpret_cast<const bf16x8*>(&Bs[(wc * 64 + n * 16 + ln15) * 32 + kq * 8]);
        #pragma unroll
        for (int m = 0; m < 4; ++m)
            #pragma unroll
            for (int n = 0; n < 4; ++n)
                acc[m][n] = __builtin_amdgcn_mfma_f32_16x16x32_bf16(af[m], bf[n], acc[m][n], 0, 0, 0);
        __syncthreads();
    }
    #pragma unroll
    for (int m = 0; m < 4; ++m) {
        #pragma unroll
        for (int n = 0; n < 4; ++n) {
            int col = bn * 128 + wc * 64 + n * 16 + ln15;
            #pragma unroll
            for (int j = 0; j < 4; ++j) {
                int row = bm * 128 + wr * 64 + m * 16 + kq * 4 + j;
                if constexpr (OUT_BF16 != 0)
                    ((unsigned short*)C)[(size_t)row * N + col] = f2bf(acc[m][n][j]);
                else
                    ((float*)C)[(size_t)row * N + col] = acc[m][n][j];
            }
        }
    }
}

// ---------------- RoPE cos/sin table: [S][32] float2 ----------------
__global__ __launch_bounds__(256) void rope_table(const int* __restrict__ pos,
                                                  float2* __restrict__ tab) {
    int idx = blockIdx.x * 256 + threadIdx.x;  // s*32 + i
    int s = idx >> 5, i = idx & 31;
    float fpos = (float)pos[s];
    float freq = exp2f(-(float)i * (13.287712379549449f / 32.0f));  // theta^(-i/32)
    float ang = fpos * freq, sn, cs;
    sincosf(ang, &sn, &cs);
    tab[idx] = make_float2(cs, sn);
}

// ---------------- RoPE + split qkv[B*S][3072] -> Qh,Kh [B,H,S,64] ----------------
__global__ __launch_bounds__(256) void rope_kernel(
    const unsigned short* __restrict__ qkv, const float2* __restrict__ tab,
    unsigned short* __restrict__ Qh, unsigned short* __restrict__ Kh) {
    int bs = blockIdx.x;            // b*SEQ + s
    int b = bs >> 11, s = bs & (SEQ - 1);
    int t = threadIdx.x;
    #pragma unroll
    for (int p = t; p < 512; p += 256) {
        int h = p >> 5, i = p & 31;
        float2 cs = tab[(s << 5) + i];
        size_t src = (size_t)bs * 3072 + h * 64 + 2 * i;
        size_t dst = ((size_t)(b * NH + h) * SEQ + s) * 64 + 2 * i;
        ushort2 qv = *reinterpret_cast<const ushort2*>(qkv + src);
        float q0 = bf2f(qv.x), q1 = bf2f(qv.y);
        ushort2 qo;
        qo.x = f2bf((q0 * cs.x - q1 * cs.y) * QSCALE);
        qo.y = f2bf((q1 * cs.x + q0 * cs.y) * QSCALE);
        *reinterpret_cast<ushort2*>(Qh + dst) = qo;
        ushort2 kv = *reinterpret_cast<const ushort2*>(qkv + src + 1024);
        float k0 = bf2f(kv.x), k1 = bf2f(kv.y);
        ushort2 ko;
        ko.x = f2bf(k0 * cs.x - k1 * cs.y);
        ko.y = f2bf(k1 * cs.x + k0 * cs.y);
        *reinterpret_cast<ushort2*>(Kh + dst) = ko;
    }
}

// ---------------- V: qkv cols 2048.. -> [B,H,64,S] (tiled transpose) ----------------
__global__ __launch_bounds__(256) void vtrans_kernel(
    const unsigned short* __restrict__ qkv, unsigned short* __restrict__ Vo) {
    __shared__ unsigned short tile[64][65];
    int blk = blockIdx.x;           // (b*NH + h)*32 + st
    int st = blk & 31, bh = blk >> 5;
    int sb = st * 64;
    int t = threadIdx.x;
    int b = bh >> 4, h = bh & 15;
    #pragma unroll
    for (int u = t; u < 1024; u += 256) {
        int sl = u >> 4, d4 = (u & 15) << 2;
        ushort4 v = *reinterpret_cast<const ushort4*>(
            qkv + (size_t)(b * SEQ + sb + sl) * 3072 + 2048 + h * 64 + d4);
        tile[sl][d4] = v.x; tile[sl][d4 + 1] = v.y;
        tile[sl][d4 + 2] = v.z; tile[sl][d4 + 3] = v.w;
    }
    __syncthreads();
    #pragma unroll
    for (int u = t; u < 1024; u += 256) {
        int d = u >> 4, s4 = (u & 15) << 2;
        ushort4 o;
        o.x = tile[s4][d]; o.y = tile[s4 + 1][d];
        o.z = tile[s4 + 2][d]; o.w = tile[s4 + 3][d];
        *reinterpret_cast<ushort4*>(Vo + ((size_t)bh * 64 + d) * SEQ + sb + s4) = o;
    }
}

// ---------------- causal flash attention, LDS-staged K/V, swapped QK^T,
//                  P redistributed via lane shuffles (no LDS round-trip) -------
// 2 waves/block, band of 32 q rows (16/wave). After mfma(K,Q), lane (q=ln15,g)
// holds P[q][4g+j] (s0) and P[q][16+4g+j] (s1). The PV A-frag needs lane
// (q,g) to hold P[q][8g..8g+7] -- a pure exchange among the 4 lanes sharing
// ln15: srcA = ln15+32(g&1), srcB = srcA+16, pick k<16 pair iff g<2.
__global__ __launch_bounds__(128) void attn_kernel(
    const unsigned short* __restrict__ Qh, const unsigned short* __restrict__ Kh,
    const unsigned short* __restrict__ Vt, unsigned short* __restrict__ Out) {
    __shared__ unsigned short Kb[2][32 * 64];   // [k][d], slot-swizzled
    __shared__ unsigned short Vb[2][64 * 32];   // [d][k], slot-swizzled

    const int tid = threadIdx.x;
    const int wid = tid >> 6, lane = tid & 63;
    const int ln15 = lane & 15, g = lane >> 4;
    const int bid = blockIdx.x;
    const int bh = bid & 31;
    const int band = 63 - (bid >> 5);           // longest-work-first, 32 q rows
    const int qb = band * 32 + wid * 16;
    const int nt = band + 1;                    // 32-wide k-tiles for this block

    const unsigned short* Qp = Qh + (size_t)bh * SEQ * 64;
    const unsigned short* Kp = Kh + (size_t)bh * SEQ * 64;
    const unsigned short* Vp = Vt + (size_t)bh * 64 * SEQ;

    // --- staging: 256 chunks x 16B per tile, 128 threads -> 2 chunks each ---
    const int c0 = tid, c1 = tid + 128;
    const unsigned short* kSrc0 = Kp + (size_t)(c0 >> 3) * 64 + (((c0 & 7) ^ ((c0 >> 3) & 7)) << 3);
    const unsigned short* kSrc1 = Kp + (size_t)(c1 >> 3) * 64 + (((c1 & 7) ^ ((c1 >> 3) & 7)) << 3);
    const unsigned short* vSrc0 = Vp + (size_t)(c0 >> 2) * SEQ + (((c0 & 3) ^ (((c0 >> 2) >> 1) & 3)) << 3);
    const unsigned short* vSrc1 = Vp + (size_t)(c1 >> 2) * SEQ + (((c1 & 3) ^ (((c1 >> 2) >> 1) & 3)) << 3);
    const unsigned base0 = (unsigned)wid * 1024;          // chunks 0..127
    const unsigned base1 = 2048 + (unsigned)wid * 1024;   // chunks 128..255

    auto stage = [&](int kb, int buf) {
        gload_lds16(kSrc0 + (size_t)kb * 64, (char*)Kb[buf] + base0);
        gload_lds16(kSrc1 + (size_t)kb * 64, (char*)Kb[buf] + base1);
        gload_lds16(vSrc0 + kb, (char*)Vb[buf] + base0);
        gload_lds16(vSrc1 + kb, (char*)Vb[buf] + base1);
    };

    // --- compute-side LDS byte offsets (fixed per lane) ---
    const int r0 = ln15, r1 = ln15 + 16;
    const unsigned kOff0a = r0 * 128 + ((g ^ (r0 & 7)) << 4);
    const unsigned kOff0b = r0 * 128 + (((4 + g) ^ (r0 & 7)) << 4);
    const unsigned kOff1a = r1 * 128 + ((g ^ (r1 & 7)) << 4);
    const unsigned kOff1b = r1 * 128 + (((4 + g) ^ (r1 & 7)) << 4);
    unsigned vOff[4];
    #pragma unroll
    for (int c = 0; c < 4; ++c) {
        int d = c * 16 + ln15;
        vOff[c] = d * 64 + ((g ^ ((d >> 1) & 3)) << 4);
    }

    bf16x8 aq0 = *reinterpret_cast<const bf16x8*>(Qp + (size_t)(qb + ln15) * 64 + g * 8);
    bf16x8 aq1 = *reinterpret_cast<const bf16x8*>(Qp + (size_t)(qb + ln15) * 64 + 32 + g * 8);

    f32x4 oacc[4] = {};
    float lsum = 0.f;
    const int thr = qb + ln15 - 4 * g;   // allowed: kb + 4g + j <= qb + ln15
    const int srcA = ln15 + ((g & 1) << 5);  // shuffle sources (lane ids)
    const int srcB = srcA + 16;
    const bool gLo = (g < 2);

    stage(0, 0);   // prologue

    for (int t = 0; t < nt; ++t) {
        const int kb = t << 5;
        const int cur = t & 1, nxt = cur ^ 1;
        {
            int tn = t + 1; if (tn > nt - 1) tn = nt - 1;   // clamped re-stage
            stage(tn << 5, nxt);
        }
        asm volatile("s_waitcnt vmcnt(4)" ::: "memory");   // tile t's 4 loads done
        __builtin_amdgcn_s_barrier();

        const unsigned short* K0 = Kb[cur];
        const unsigned short* V0 = Vb[cur];
        const f32x4 z = {};
        bf16x8 kf0 = *reinterpret_cast<const bf16x8*>((const char*)K0 + kOff0a);
        bf16x8 kf1 = *reinterpret_cast<const bf16x8*>((const char*)K0 + kOff0b);
        bf16x8 kf2 = *reinterpret_cast<const bf16x8*>((const char*)K0 + kOff1a);
        bf16x8 kf3 = *reinterpret_cast<const bf16x8*>((const char*)K0 + kOff1b);
        f32x4 s0, s1;
        s0 = __builtin_amdgcn_mfma_f32_16x16x32_bf16(kf0, aq0, z, 0, 0, 0);
        s0 = __builtin_amdgcn_mfma_f32_16x16x32_bf16(kf1, aq1, s0, 0, 0, 0);
        s1 = __builtin_amdgcn_mfma_f32_16x16x32_bf16(kf2, aq0, z, 0, 0, 0);
        s1 = __builtin_amdgcn_mfma_f32_16x16x32_bf16(kf3, aq1, s1, 0, 0, 0);

        float p0[4], p1[4];
        if (t == band) {     // only the boundary tile needs the causal mask
            #pragma unroll
            for (int j = 0; j < 4; ++j) {
                p0[j] = (j <= thr - kb) ? EXP2(s0[j]) : 0.f;
                p1[j] = (j <= thr - kb - 16) ? EXP2(s1[j]) : 0.f;
            }
        } else {
            #pragma unroll
            for (int j = 0; j < 4; ++j) { p0[j] = EXP2(s0[j]); p1[j] = EXP2(s1[j]); }
        }
        lsum += (p0[0] + p0[1]) + (p0[2] + p0[3]) + (p1[0] + p1[1]) + (p1[2] + p1[3]);

        // pack P into bf16 pairs and redistribute among the 4 lanes of this q
        unsigned A0 = packbf(p0[0], p0[1]), A1 = packbf(p0[2], p0[3]);
        unsigned B0 = packbf(p1[0], p1[1]), B1 = packbf(p1[2], p1[3]);
        unsigned ra0 = (unsigned)__shfl((int)A0, srcA), rb0 = (unsigned)__shfl((int)B0, srcA);
        unsigned ra1 = (unsigned)__shfl((int)A1, srcA), rb1 = (unsigned)__shfl((int)B1, srcA);
        unsigned ra2 = (unsigned)__shfl((int)A0, srcB), rb2 = (unsigned)__shfl((int)B0, srcB);
        unsigned ra3 = (unsigned)__shfl((int)A1, srcB), rb3 = (unsigned)__shfl((int)B1, srcB);
        union { unsigned u[4]; bf16x8 v; } apu;
        apu.u[0] = gLo ? ra0 : rb0;
        apu.u[1] = gLo ? ra1 : rb1;
        apu.u[2] = gLo ? ra2 : rb2;
        apu.u[3] = gLo ? ra3 : rb3;
        bf16x8 ap = apu.v;

        #pragma unroll
        for (int c = 0; c < 4; ++c) {
            bf16x8 bv = *reinterpret_cast<const bf16x8*>((const char*)V0 + vOff[c]);
            oacc[c] = __builtin_amdgcn_mfma_f32_16x16x32_bf16(ap, bv, oacc[c], 0, 0, 0);
        }
        asm volatile("s_waitcnt lgkmcnt(0)" ::: "memory");  // K/V reads of cur done
        __builtin_amdgcn_s_barrier();
    }

    // row sum split across the 4 g-lanes of each ln15: reduce, invert,
    // redistribute to the (g,j) layout of the O accumulator rows.
    float r = lsum;
    r += __shfl_xor(r, 16);
    r += __shfl_xor(r, 32);
    float linv = 1.f / r;
    float invj[4];
    #pragma unroll
    for (int j = 0; j < 4; ++j)
        invj[j] = __shfl(linv, 20 * g + j);   // lane with ln15 == 4g+j

    int b = bh >> 4, h = bh & 15;
    #pragma unroll
    for (int c = 0; c < 4; ++c)
        #pragma unroll
        for (int j = 0; j < 4; ++j) {
            int s = qb + g * 4 + j;
            Out[((size_t)(b * SEQ + s)) * DM + h * 64 + c * 16 + ln15] =
                f2bf(oacc[c][j] * invj[j]);
        }
}

extern "C" void kernel_launch(void* const* d_in, const int* in_sizes, int n_in,
                              void* d_out, int out_size, void* d_ws, size_t ws_size,
                              hipStream_t stream) {
    const float* x = (const float*)d_in[0];
    const int* pos = (const int*)d_in[1];
    const float* Wq = (const float*)d_in[2];
    const float* Wk = (const float*)d_in[3];
    const float* Wv = (const float*)d_in[4];
    const float* Wo = (const float*)d_in[5];
    float* out = (float*)d_out;

    char* ws = (char*)d_ws;
    const size_t MB = 1024 * 1024;
    unsigned short* xb   = (unsigned short*)(ws + 0 * MB);
    unsigned short* wqkv = (unsigned short*)(ws + 8 * MB);   // wq|wk|wv contiguous
    unsigned short* wob  = (unsigned short*)(ws + 14 * MB);
    unsigned short* qkv  = (unsigned short*)(ws + 16 * MB);  // [4096][3072]
    float2*         tab  = (float2*)       (ws + 40 * MB);   // [2048][32]
    unsigned short* qh   = (unsigned short*)(ws + 41 * MB);
    unsigned short* kh   = (unsigned short*)(ws + 49 * MB);
    unsigned short* vtr  = (unsigned short*)(ws + 57 * MB);
    unsigned short* att  = (unsigned short*)(ws + 65 * MB);

    cvt_all<<<8192, 256, 0, stream>>>(x, Wq, Wk, Wv, Wo, xb, wqkv, wob);
    rope_table<<<256, 256, 0, stream>>>(pos, tab);

    gemm_bt<1><<<dim3(24, 32), 256, 0, stream>>>(xb, wqkv, qkv, 4096, 3072, 1024);

    rope_kernel<<<4096, 256, 0, stream>>>(qkv, tab, qh, kh);
    vtrans_kernel<<<1024, 256, 0, stream>>>(qkv, vtr);

    attn_kernel<<<2048, 128, 0, stream>>>(qh, kh, vtr, att);

    gemm_bt<0><<<dim3(8, 32), 256, 0, stream>>>(att, wob, out, 4096, 1024, 1024);
}

// Round 8
// 130.821 us; speedup vs baseline: 1.0372x; 1.0372x over previous
//
#include <hip/hip_runtime.h>
#include <hip/hip_bf16.h>
#include <cstdint>
#include <cmath>

#define SEQ 2048
#define NH 16
#define DM 1024
#define BATCH 2

typedef short bf16x8 __attribute__((ext_vector_type(8)));
typedef float f32x4 __attribute__((ext_vector_type(4)));
typedef const void __attribute__((address_space(1)))* gas_t;
typedef void __attribute__((address_space(3)))* las_t;

#if __has_builtin(__builtin_amdgcn_exp2f)
#define EXP2(x) __builtin_amdgcn_exp2f(x)
#else
#define EXP2(x) __expf((x) * 0.6931471805599453f)
#endif

// Q prescale: (1/sqrt(64)) * log2(e) so scores are already in log2 domain
#define QSCALE 0.18033688011112042f

static __device__ __forceinline__ unsigned short f2bf(float f) {
    union { __hip_bfloat16 h; unsigned short u; } cv;
    cv.h = __float2bfloat16(f);
    return cv.u;
}
static __device__ __forceinline__ float bf2f(unsigned short u) {
    union { unsigned short u; __hip_bfloat16 h; } cv;
    cv.u = u;
    return __bfloat162float(cv.h);
}

static __device__ __forceinline__ void gload_lds16(const void* g, void* l) {
    __builtin_amdgcn_global_load_lds(
        reinterpret_cast<gas_t>(reinterpret_cast<uintptr_t>(g)),
        reinterpret_cast<las_t>(reinterpret_cast<uintptr_t>(l)),
        16, 0, 0);
}

// ---------------- fp32 -> bf16 convert, all 5 tensors in one launch ----------
__global__ __launch_bounds__(256) void cvt_all(
    const float* __restrict__ x,  const float* __restrict__ wq,
    const float* __restrict__ wk, const float* __restrict__ wv,
    const float* __restrict__ wo,
    unsigned short* __restrict__ xb, unsigned short* __restrict__ wqkv,
    unsigned short* __restrict__ wob) {
    int blk = blockIdx.x;
    const float* src; unsigned short* dst; int base;
    if (blk < 4096)      { src = x;  dst = xb;              base = blk; }
    else if (blk < 5120) { src = wq; dst = wqkv;            base = blk - 4096; }
    else if (blk < 6144) { src = wk; dst = wqkv + 1048576;  base = blk - 5120; }
    else if (blk < 7168) { src = wv; dst = wqkv + 2097152;  base = blk - 6144; }
    else                 { src = wo; dst = wob;             base = blk - 7168; }
    int i = base * 256 + threadIdx.x;
    float4 v = reinterpret_cast<const float4*>(src)[i];
    ushort4 o;
    o.x = f2bf(v.x); o.y = f2bf(v.y); o.z = f2bf(v.z); o.w = f2bf(v.w);
    reinterpret_cast<ushort4*>(dst)[i] = o;
}

// ---------------- bf16 GEMM: C[M][N] = A[M][K] * B[N][K]^T ----------------
template<int OUT_BF16>
__global__ __launch_bounds__(256) void gemm_bt(
    const unsigned short* __restrict__ A,
    const unsigned short* __restrict__ B,
    void* __restrict__ C, int M, int N, int K) {
    __shared__ unsigned short As[128 * 32];
    __shared__ unsigned short Bs[128 * 32];
    const int tid = threadIdx.x;
    const int lane = tid & 63, wid = tid >> 6;
    const int wr = wid >> 1, wc = wid & 1;
    const int ln15 = lane & 15, kq = lane >> 4;
    const int bm = blockIdx.y, bn = blockIdx.x;

    f32x4 acc[4][4] = {};
    const int nk = K >> 5;
    for (int kt = 0; kt < nk; ++kt) {
        #pragma unroll
        for (int i = 0; i < 2; ++i) {
            int c = i * 256 + tid;
            int row = c >> 2, k8 = (c & 3) << 3;
            size_t gofsA = (size_t)(bm * 128 + row) * K + kt * 32 + k8;
            size_t gofsB = (size_t)(bn * 128 + row) * K + kt * 32 + k8;
            unsigned ldsoff = (unsigned)(i * 256 + wid * 64) * 16;  // wave-uniform
            gload_lds16(A + gofsA, (char*)As + ldsoff);
            gload_lds16(B + gofsB, (char*)Bs + ldsoff);
        }
        __syncthreads();
        bf16x8 af[4], bf[4];
        #pragma unroll
        for (int m = 0; m < 4; ++m)
            af[m] = *reinterpret_cast<const bf16x8*>(&As[(wr * 64 + m * 16 + ln15) * 32 + kq * 8]);
        #pragma unroll
        for (int n = 0; n < 4; ++n)
            bf[n] = *reinterpret_cast<const bf16x8*>(&Bs[(wc * 64 + n * 16 + ln15) * 32 + kq * 8]);
        #pragma unroll
        for (int m = 0; m < 4; ++m)
            #pragma unroll
            for (int n = 0; n < 4; ++n)
                acc[m][n] = __builtin_amdgcn_mfma_f32_16x16x32_bf16(af[m], bf[n], acc[m][n], 0, 0, 0);
        __syncthreads();
    }
    #pragma unroll
    for (int m = 0; m < 4; ++m) {
        #pragma unroll
        for (int n = 0; n < 4; ++n) {
            int col = bn * 128 + wc * 64 + n * 16 + ln15;
            #pragma unroll
            for (int j = 0; j < 4; ++j) {
                int row = bm * 128 + wr * 64 + m * 16 + kq * 4 + j;
                if constexpr (OUT_BF16 != 0)
                    ((unsigned short*)C)[(size_t)row * N + col] = f2bf(acc[m][n][j]);
                else
                    ((float*)C)[(size_t)row * N + col] = acc[m][n][j];
            }
        }
    }
}

// ---------------- RoPE cos/sin table: [S][32] float2 ----------------
__global__ __launch_bounds__(256) void rope_table(const int* __restrict__ pos,
                                                  float2* __restrict__ tab) {
    int idx = blockIdx.x * 256 + threadIdx.x;  // s*32 + i
    int s = idx >> 5, i = idx & 31;
    float fpos = (float)pos[s];
    float freq = exp2f(-(float)i * (13.287712379549449f / 32.0f));  // theta^(-i/32)
    float ang = fpos * freq, sn, cs;
    sincosf(ang, &sn, &cs);
    tab[idx] = make_float2(cs, sn);
}

// ---------------- RoPE + split qkv[B*S][3072] -> Qh,Kh [B,H,S,64] ----------------
__global__ __launch_bounds__(256) void rope_kernel(
    const unsigned short* __restrict__ qkv, const float2* __restrict__ tab,
    unsigned short* __restrict__ Qh, unsigned short* __restrict__ Kh) {
    int bs = blockIdx.x;            // b*SEQ + s
    int b = bs >> 11, s = bs & (SEQ - 1);
    int t = threadIdx.x;
    #pragma unroll
    for (int p = t; p < 512; p += 256) {
        int h = p >> 5, i = p & 31;
        float2 cs = tab[(s << 5) + i];
        size_t src = (size_t)bs * 3072 + h * 64 + 2 * i;
        size_t dst = ((size_t)(b * NH + h) * SEQ + s) * 64 + 2 * i;
        ushort2 qv = *reinterpret_cast<const ushort2*>(qkv + src);
        float q0 = bf2f(qv.x), q1 = bf2f(qv.y);
        ushort2 qo;
        qo.x = f2bf((q0 * cs.x - q1 * cs.y) * QSCALE);
        qo.y = f2bf((q1 * cs.x + q0 * cs.y) * QSCALE);
        *reinterpret_cast<ushort2*>(Qh + dst) = qo;
        ushort2 kv = *reinterpret_cast<const ushort2*>(qkv + src + 1024);
        float k0 = bf2f(kv.x), k1 = bf2f(kv.y);
        ushort2 ko;
        ko.x = f2bf(k0 * cs.x - k1 * cs.y);
        ko.y = f2bf(k1 * cs.x + k0 * cs.y);
        *reinterpret_cast<ushort2*>(Kh + dst) = ko;
    }
}

// ---------------- V: qkv cols 2048.. -> [B,H,64,S] (tiled transpose) ----------------
__global__ __launch_bounds__(256) void vtrans_kernel(
    const unsigned short* __restrict__ qkv, unsigned short* __restrict__ Vo) {
    __shared__ unsigned short tile[64][65];
    int blk = blockIdx.x;           // (b*NH + h)*32 + st
    int st = blk & 31, bh = blk >> 5;
    int sb = st * 64;
    int t = threadIdx.x;
    int b = bh >> 4, h = bh & 15;
    #pragma unroll
    for (int u = t; u < 1024; u += 256) {
        int sl = u >> 4, d4 = (u & 15) << 2;
        ushort4 v = *reinterpret_cast<const ushort4*>(
            qkv + (size_t)(b * SEQ + sb + sl) * 3072 + 2048 + h * 64 + d4);
        tile[sl][d4] = v.x; tile[sl][d4 + 1] = v.y;
        tile[sl][d4 + 2] = v.z; tile[sl][d4 + 3] = v.w;
    }
    __syncthreads();
    #pragma unroll
    for (int u = t; u < 1024; u += 256) {
        int d = u >> 4, s4 = (u & 15) << 2;
        ushort4 o;
        o.x = tile[s4][d]; o.y = tile[s4 + 1][d];
        o.z = tile[s4 + 2][d]; o.w = tile[s4 + 3][d];
        *reinterpret_cast<ushort4*>(Vo + ((size_t)bh * 64 + d) * SEQ + sb + s4) = o;
    }
}

// ---------------- causal flash attention, folded band pairs -------------------
// Block (bh, fold i) handles TWO 32-row q-bands: lo = i, hi = 63-i. Every block
// does exactly 65 tile-band computations (uniform work, no causal tail). Per
// staged k-tile both bands reuse the same K-frags / V-frags: up to 16 MFMAs per
// wave per tile. K/V staged via global_load_lds (linear dest, inverse-swizzled
// source), double-buffered, counted vmcnt. Swapped QK^T (mfma(K,Q)); P goes
// through per-wave, per-band LDS regions (one lgkmcnt drain covers both).
__global__ __launch_bounds__(128) void attn_kernel(
    const unsigned short* __restrict__ Qh, const unsigned short* __restrict__ Kh,
    const unsigned short* __restrict__ Vt, unsigned short* __restrict__ Out) {
    __shared__ unsigned short Kb[2][32 * 64];      // [k][d], slot-swizzled
    __shared__ unsigned short Vb[2][64 * 32];      // [d][k], slot-swizzled
    __shared__ unsigned short Plds[2][2][16 * 40]; // [wid][band]

    const int tid = threadIdx.x;
    const int wid = tid >> 6, lane = tid & 63;
    const int ln15 = lane & 15, g = lane >> 4;
    const int bid = blockIdx.x;
    const int bh = bid & 31;
    const int fold = bid >> 5;                  // 0..31
    const int qbL = fold * 32 + wid * 16;       // lo band rows
    const int qbH = (63 - fold) * 32 + wid * 16;// hi band rows
    const int nt = 64 - fold;                   // staged 32-wide k-tiles

    const unsigned short* Qp = Qh + (size_t)bh * SEQ * 64;
    const unsigned short* Kp = Kh + (size_t)bh * SEQ * 64;
    const unsigned short* Vp = Vt + (size_t)bh * 64 * SEQ;
    unsigned short* PL = Plds[wid][0];
    unsigned short* PH = Plds[wid][1];

    // --- staging: 256 chunks x 16B per tile, 128 threads -> 2 chunks each ---
    const int c0 = tid, c1 = tid + 128;
    const unsigned short* kSrc0 = Kp + (size_t)(c0 >> 3) * 64 + (((c0 & 7) ^ ((c0 >> 3) & 7)) << 3);
    const unsigned short* kSrc1 = Kp + (size_t)(c1 >> 3) * 64 + (((c1 & 7) ^ ((c1 >> 3) & 7)) << 3);
    const unsigned short* vSrc0 = Vp + (size_t)(c0 >> 2) * SEQ + (((c0 & 3) ^ (((c0 >> 2) >> 1) & 3)) << 3);
    const unsigned short* vSrc1 = Vp + (size_t)(c1 >> 2) * SEQ + (((c1 & 3) ^ (((c1 >> 2) >> 1) & 3)) << 3);
    const unsigned base0 = (unsigned)wid * 1024;          // chunks 0..127
    const unsigned base1 = 2048 + (unsigned)wid * 1024;   // chunks 128..255

    auto stage = [&](int kb, int buf) {
        gload_lds16(kSrc0 + (size_t)kb * 64, (char*)Kb[buf] + base0);
        gload_lds16(kSrc1 + (size_t)kb * 64, (char*)Kb[buf] + base1);
        gload_lds16(vSrc0 + kb, (char*)Vb[buf] + base0);
        gload_lds16(vSrc1 + kb, (char*)Vb[buf] + base1);
    };

    // --- compute-side LDS byte offsets (fixed per lane) ---
    const int r0 = ln15, r1 = ln15 + 16;
    const unsigned kOff0a = r0 * 128 + ((g ^ (r0 & 7)) << 4);
    const unsigned kOff0b = r0 * 128 + (((4 + g) ^ (r0 & 7)) << 4);
    const unsigned kOff1a = r1 * 128 + ((g ^ (r1 & 7)) << 4);
    const unsigned kOff1b = r1 * 128 + (((4 + g) ^ (r1 & 7)) << 4);
    unsigned vOff[4];
    #pragma unroll
    for (int c = 0; c < 4; ++c) {
        int d = c * 16 + ln15;
        vOff[c] = d * 64 + ((g ^ ((d >> 1) & 3)) << 4);
    }

    bf16x8 aqL0 = *reinterpret_cast<const bf16x8*>(Qp + (size_t)(qbL + ln15) * 64 + g * 8);
    bf16x8 aqL1 = *reinterpret_cast<const bf16x8*>(Qp + (size_t)(qbL + ln15) * 64 + 32 + g * 8);
    bf16x8 aqH0 = *reinterpret_cast<const bf16x8*>(Qp + (size_t)(qbH + ln15) * 64 + g * 8);
    bf16x8 aqH1 = *reinterpret_cast<const bf16x8*>(Qp + (size_t)(qbH + ln15) * 64 + 32 + g * 8);

    f32x4 oaccL[4] = {}, oaccH[4] = {};
    float lsumL = 0.f, lsumH = 0.f;
    const int thrL = qbL + ln15 - 4 * g;   // allowed: kb + 4g + j <= qb + ln15
    const int thrH = qbH + ln15 - 4 * g;

    stage(0, 0);   // prologue

    for (int t = 0; t < nt; ++t) {
        const int kb = t << 5;
        const int cur = t & 1, nxt = cur ^ 1;
        {
            int tn = t + 1; if (tn > nt - 1) tn = nt - 1;   // clamped re-stage
            stage(tn << 5, nxt);
        }
        asm volatile("s_waitcnt vmcnt(4)" ::: "memory");   // tile t's 4 loads done
        __builtin_amdgcn_s_barrier();

        const unsigned short* K0 = Kb[cur];
        const unsigned short* V0 = Vb[cur];
        const f32x4 z = {};
        bf16x8 kf0 = *reinterpret_cast<const bf16x8*>((const char*)K0 + kOff0a);
        bf16x8 kf1 = *reinterpret_cast<const bf16x8*>((const char*)K0 + kOff0b);
        bf16x8 kf2 = *reinterpret_cast<const bf16x8*>((const char*)K0 + kOff1a);
        bf16x8 kf3 = *reinterpret_cast<const bf16x8*>((const char*)K0 + kOff1b);
        bf16x8 bv0 = *reinterpret_cast<const bf16x8*>((const char*)V0 + vOff[0]);
        bf16x8 bv1 = *reinterpret_cast<const bf16x8*>((const char*)V0 + vOff[1]);
        bf16x8 bv2 = *reinterpret_cast<const bf16x8*>((const char*)V0 + vOff[2]);
        bf16x8 bv3 = *reinterpret_cast<const bf16x8*>((const char*)V0 + vOff[3]);

        const bool loAct = (t <= fold);

        // ---- QK^T (swapped): lane holds q = qb+ln15, k = kb+4g+j / kb+16+4g+j
        f32x4 sH0, sH1, sL0, sL1;
        sH0 = __builtin_amdgcn_mfma_f32_16x16x32_bf16(kf0, aqH0, z, 0, 0, 0);
        sH0 = __builtin_amdgcn_mfma_f32_16x16x32_bf16(kf1, aqH1, sH0, 0, 0, 0);
        sH1 = __builtin_amdgcn_mfma_f32_16x16x32_bf16(kf2, aqH0, z, 0, 0, 0);
        sH1 = __builtin_amdgcn_mfma_f32_16x16x32_bf16(kf3, aqH1, sH1, 0, 0, 0);
        if (loAct) {
            sL0 = __builtin_amdgcn_mfma_f32_16x16x32_bf16(kf0, aqL0, z, 0, 0, 0);
            sL0 = __builtin_amdgcn_mfma_f32_16x16x32_bf16(kf1, aqL1, sL0, 0, 0, 0);
            sL1 = __builtin_amdgcn_mfma_f32_16x16x32_bf16(kf2, aqL0, z, 0, 0, 0);
            sL1 = __builtin_amdgcn_mfma_f32_16x16x32_bf16(kf3, aqL1, sL1, 0, 0, 0);
        }

        // ---- softmax numerators + P stores (both bands under one drain) ----
        {
            float p0[4], p1[4];
            if (t == nt - 1) {   // hi boundary tile
                #pragma unroll
                for (int j = 0; j < 4; ++j) {
                    p0[j] = (j <= thrH - kb) ? EXP2(sH0[j]) : 0.f;
                    p1[j] = (j <= thrH - kb - 16) ? EXP2(sH1[j]) : 0.f;
                }
            } else {
                #pragma unroll
                for (int j = 0; j < 4; ++j) { p0[j] = EXP2(sH0[j]); p1[j] = EXP2(sH1[j]); }
            }
            lsumH += (p0[0] + p0[1]) + (p0[2] + p0[3]) + (p1[0] + p1[1]) + (p1[2] + p1[3]);
            ushort4 w0, w1;
            w0.x = f2bf(p0[0]); w0.y = f2bf(p0[1]); w0.z = f2bf(p0[2]); w0.w = f2bf(p0[3]);
            w1.x = f2bf(p1[0]); w1.y = f2bf(p1[1]); w1.z = f2bf(p1[2]); w1.w = f2bf(p1[3]);
            *reinterpret_cast<ushort4*>(&PH[ln15 * 40 + 4 * g]) = w0;
            *reinterpret_cast<ushort4*>(&PH[ln15 * 40 + 16 + 4 * g]) = w1;
        }
        if (loAct) {
            float p0[4], p1[4];
            if (t == fold) {     // lo boundary tile
                #pragma unroll
                for (int j = 0; j < 4; ++j) {
                    p0[j] = (j <= thrL - kb) ? EXP2(sL0[j]) : 0.f;
                    p1[j] = (j <= thrL - kb - 16) ? EXP2(sL1[j]) : 0.f;
                }
            } else {
                #pragma unroll
                for (int j = 0; j < 4; ++j) { p0[j] = EXP2(sL0[j]); p1[j] = EXP2(sL1[j]); }
            }
            lsumL += (p0[0] + p0[1]) + (p0[2] + p0[3]) + (p1[0] + p1[1]) + (p1[2] + p1[3]);
            ushort4 w0, w1;
            w0.x = f2bf(p0[0]); w0.y = f2bf(p0[1]); w0.z = f2bf(p0[2]); w0.w = f2bf(p0[3]);
            w1.x = f2bf(p1[0]); w1.y = f2bf(p1[1]); w1.z = f2bf(p1[2]); w1.w = f2bf(p1[3]);
            *reinterpret_cast<ushort4*>(&PL[ln15 * 40 + 4 * g]) = w0;
            *reinterpret_cast<ushort4*>(&PL[ln15 * 40 + 16 + 4 * g]) = w1;
        }
        asm volatile("s_waitcnt lgkmcnt(0)" ::: "memory");

        // ---- PV for both bands, shared V-frags ----
        bf16x8 apH = *reinterpret_cast<const bf16x8*>(&PH[ln15 * 40 + 8 * g]);
        oaccH[0] = __builtin_amdgcn_mfma_f32_16x16x32_bf16(apH, bv0, oaccH[0], 0, 0, 0);
        oaccH[1] = __builtin_amdgcn_mfma_f32_16x16x32_bf16(apH, bv1, oaccH[1], 0, 0, 0);
        oaccH[2] = __builtin_amdgcn_mfma_f32_16x16x32_bf16(apH, bv2, oaccH[2], 0, 0, 0);
        oaccH[3] = __builtin_amdgcn_mfma_f32_16x16x32_bf16(apH, bv3, oaccH[3], 0, 0, 0);
        if (loAct) {
            bf16x8 apL = *reinterpret_cast<const bf16x8*>(&PL[ln15 * 40 + 8 * g]);
            oaccL[0] = __builtin_amdgcn_mfma_f32_16x16x32_bf16(apL, bv0, oaccL[0], 0, 0, 0);
            oaccL[1] = __builtin_amdgcn_mfma_f32_16x16x32_bf16(apL, bv1, oaccL[1], 0, 0, 0);
            oaccL[2] = __builtin_amdgcn_mfma_f32_16x16x32_bf16(apL, bv2, oaccL[2], 0, 0, 0);
            oaccL[3] = __builtin_amdgcn_mfma_f32_16x16x32_bf16(apL, bv3, oaccL[3], 0, 0, 0);
        }
        asm volatile("s_waitcnt lgkmcnt(0)" ::: "memory");  // all LDS reads of cur done
        __builtin_amdgcn_s_barrier();
    }

    // row sums split across the 4 g-lanes of each ln15: reduce, invert,
    // redistribute to the (g,j) layout of the O accumulator rows.
    int b = bh >> 4, h = bh & 15;
    {
        float r = lsumH;
        r += __shfl_xor(r, 16);
        r += __shfl_xor(r, 32);
        float linv = 1.f / r;
        float invj[4];
        #pragma unroll
        for (int j = 0; j < 4; ++j)
            invj[j] = __shfl(linv, 20 * g + j);   // lane with ln15 == 4g+j
        #pragma unroll
        for (int c = 0; c < 4; ++c)
            #pragma unroll
            for (int j = 0; j < 4; ++j) {
                int s = qbH + g * 4 + j;
                Out[((size_t)(b * SEQ + s)) * DM + h * 64 + c * 16 + ln15] =
                    f2bf(oaccH[c][j] * invj[j]);
            }
    }
    {
        float r = lsumL;
        r += __shfl_xor(r, 16);
        r += __shfl_xor(r, 32);
        float linv = 1.f / r;
        float invj[4];
        #pragma unroll
        for (int j = 0; j < 4; ++j)
            invj[j] = __shfl(linv, 20 * g + j);
        #pragma unroll
        for (int c = 0; c < 4; ++c)
            #pragma unroll
            for (int j = 0; j < 4; ++j) {
                int s = qbL + g * 4 + j;
                Out[((size_t)(b * SEQ + s)) * DM + h * 64 + c * 16 + ln15] =
                    f2bf(oaccL[c][j] * invj[j]);
            }
    }
}

extern "C" void kernel_launch(void* const* d_in, const int* in_sizes, int n_in,
                              void* d_out, int out_size, void* d_ws, size_t ws_size,
                              hipStream_t stream) {
    const float* x = (const float*)d_in[0];
    const int* pos = (const int*)d_in[1];
    const float* Wq = (const float*)d_in[2];
    const float* Wk = (const float*)d_in[3];
    const float* Wv = (const float*)d_in[4];
    const float* Wo = (const float*)d_in[5];
    float* out = (float*)d_out;

    char* ws = (char*)d_ws;
    const size_t MB = 1024 * 1024;
    unsigned short* xb   = (unsigned short*)(ws + 0 * MB);
    unsigned short* wqkv = (unsigned short*)(ws + 8 * MB);   // wq|wk|wv contiguous
    unsigned short* wob  = (unsigned short*)(ws + 14 * MB);
    unsigned short* qkv  = (unsigned short*)(ws + 16 * MB);  // [4096][3072]
    float2*         tab  = (float2*)       (ws + 40 * MB);   // [2048][32]
    unsigned short* qh   = (unsigned short*)(ws + 41 * MB);
    unsigned short* kh   = (unsigned short*)(ws + 49 * MB);
    unsigned short* vtr  = (unsigned short*)(ws + 57 * MB);
    unsigned short* att  = (unsigned short*)(ws + 65 * MB);

    cvt_all<<<8192, 256, 0, stream>>>(x, Wq, Wk, Wv, Wo, xb, wqkv, wob);
    rope_table<<<256, 256, 0, stream>>>(pos, tab);

    gemm_bt<1><<<dim3(24, 32), 256, 0, stream>>>(xb, wqkv, qkv, 4096, 3072, 1024);

    rope_kernel<<<4096, 256, 0, stream>>>(qkv, tab, qh, kh);
    vtrans_kernel<<<1024, 256, 0, stream>>>(qkv, vtr);

    attn_kernel<<<1024, 128, 0, stream>>>(qh, kh, vtr, att);

    gemm_bt<0><<<dim3(8, 32), 256, 0, stream>>>(att, wob, out, 4096, 1024, 1024);
}

// Round 9
// 128.350 us; speedup vs baseline: 1.0572x; 1.0193x over previous
//
#include <hip/hip_runtime.h>
#include <hip/hip_bf16.h>
#include <cstdint>
#include <cmath>

#define SEQ 2048
#define NH 16
#define DM 1024
#define BATCH 2

typedef short bf16x8 __attribute__((ext_vector_type(8)));
typedef float f32x4 __attribute__((ext_vector_type(4)));
typedef const void __attribute__((address_space(1)))* gas_t;
typedef void __attribute__((address_space(3)))* las_t;

#if __has_builtin(__builtin_amdgcn_exp2f)
#define EXP2(x) __builtin_amdgcn_exp2f(x)
#else
#define EXP2(x) __expf((x) * 0.6931471805599453f)
#endif

// Q prescale: (1/sqrt(64)) * log2(e) so scores are already in log2 domain
#define QSCALE 0.18033688011112042f

static __device__ __forceinline__ unsigned short f2bf(float f) {
    union { __hip_bfloat16 h; unsigned short u; } cv;
    cv.h = __float2bfloat16(f);
    return cv.u;
}
static __device__ __forceinline__ float bf2f(unsigned short u) {
    union { unsigned short u; __hip_bfloat16 h; } cv;
    cv.u = u;
    return __bfloat162float(cv.h);
}

static __device__ __forceinline__ void gload_lds16(const void* g, void* l) {
    __builtin_amdgcn_global_load_lds(
        reinterpret_cast<gas_t>(reinterpret_cast<uintptr_t>(g)),
        reinterpret_cast<las_t>(reinterpret_cast<uintptr_t>(l)),
        16, 0, 0);
}

// ---------------- fp32 -> bf16 convert, all 5 tensors in one launch ----------
__global__ __launch_bounds__(256) void cvt_all(
    const float* __restrict__ x,  const float* __restrict__ wq,
    const float* __restrict__ wk, const float* __restrict__ wv,
    const float* __restrict__ wo,
    unsigned short* __restrict__ xb, unsigned short* __restrict__ wqkv,
    unsigned short* __restrict__ wob) {
    int blk = blockIdx.x;
    const float* src; unsigned short* dst; int base;
    if (blk < 4096)      { src = x;  dst = xb;              base = blk; }
    else if (blk < 5120) { src = wq; dst = wqkv;            base = blk - 4096; }
    else if (blk < 6144) { src = wk; dst = wqkv + 1048576;  base = blk - 5120; }
    else if (blk < 7168) { src = wv; dst = wqkv + 2097152;  base = blk - 6144; }
    else                 { src = wo; dst = wob;             base = blk - 7168; }
    int i = base * 256 + threadIdx.x;
    float4 v = reinterpret_cast<const float4*>(src)[i];
    ushort4 o;
    o.x = f2bf(v.x); o.y = f2bf(v.y); o.z = f2bf(v.z); o.w = f2bf(v.w);
    reinterpret_cast<ushort4*>(dst)[i] = o;
}

// ---------------- bf16 GEMM: C[M][N] = A[M][K] * B[N][K]^T ----------------
template<int OUT_BF16>
__global__ __launch_bounds__(256) void gemm_bt(
    const unsigned short* __restrict__ A,
    const unsigned short* __restrict__ B,
    void* __restrict__ C, int M, int N, int K) {
    __shared__ unsigned short As[128 * 32];
    __shared__ unsigned short Bs[128 * 32];
    const int tid = threadIdx.x;
    const int lane = tid & 63, wid = tid >> 6;
    const int wr = wid >> 1, wc = wid & 1;
    const int ln15 = lane & 15, kq = lane >> 4;
    const int bm = blockIdx.y, bn = blockIdx.x;

    f32x4 acc[4][4] = {};
    const int nk = K >> 5;
    for (int kt = 0; kt < nk; ++kt) {
        #pragma unroll
        for (int i = 0; i < 2; ++i) {
            int c = i * 256 + tid;
            int row = c >> 2, k8 = (c & 3) << 3;
            size_t gofsA = (size_t)(bm * 128 + row) * K + kt * 32 + k8;
            size_t gofsB = (size_t)(bn * 128 + row) * K + kt * 32 + k8;
            unsigned ldsoff = (unsigned)(i * 256 + wid * 64) * 16;  // wave-uniform
            gload_lds16(A + gofsA, (char*)As + ldsoff);
            gload_lds16(B + gofsB, (char*)Bs + ldsoff);
        }
        __syncthreads();
        bf16x8 af[4], bf[4];
        #pragma unroll
        for (int m = 0; m < 4; ++m)
            af[m] = *reinterpret_cast<const bf16x8*>(&As[(wr * 64 + m * 16 + ln15) * 32 + kq * 8]);
        #pragma unroll
        for (int n = 0; n < 4; ++n)
            bf[n] = *reinterpret_cast<const bf16x8*>(&Bs[(wc * 64 + n * 16 + ln15) * 32 + kq * 8]);
        #pragma unroll
        for (int m = 0; m < 4; ++m)
            #pragma unroll
            for (int n = 0; n < 4; ++n)
                acc[m][n] = __builtin_amdgcn_mfma_f32_16x16x32_bf16(af[m], bf[n], acc[m][n], 0, 0, 0);
        __syncthreads();
    }
    #pragma unroll
    for (int m = 0; m < 4; ++m) {
        #pragma unroll
        for (int n = 0; n < 4; ++n) {
            int col = bn * 128 + wc * 64 + n * 16 + ln15;
            #pragma unroll
            for (int j = 0; j < 4; ++j) {
                int row = bm * 128 + wr * 64 + m * 16 + kq * 4 + j;
                if constexpr (OUT_BF16 != 0)
                    ((unsigned short*)C)[(size_t)row * N + col] = f2bf(acc[m][n][j]);
                else
                    ((float*)C)[(size_t)row * N + col] = acc[m][n][j];
            }
        }
    }
}

// ---------------- RoPE cos/sin table: [S][32] float2 ----------------
__global__ __launch_bounds__(256) void rope_table(const int* __restrict__ pos,
                                                  float2* __restrict__ tab) {
    int idx = blockIdx.x * 256 + threadIdx.x;  // s*32 + i
    int s = idx >> 5, i = idx & 31;
    float fpos = (float)pos[s];
    float freq = exp2f(-(float)i * (13.287712379549449f / 32.0f));  // theta^(-i/32)
    float ang = fpos * freq, sn, cs;
    sincosf(ang, &sn, &cs);
    tab[idx] = make_float2(cs, sn);
}

// ---------------- RoPE + split qkv[B*S][3072] -> Qh,Kh [B,H,S,64] ----------------
__global__ __launch_bounds__(256) void rope_kernel(
    const unsigned short* __restrict__ qkv, const float2* __restrict__ tab,
    unsigned short* __restrict__ Qh, unsigned short* __restrict__ Kh) {
    int bs = blockIdx.x;            // b*SEQ + s
    int b = bs >> 11, s = bs & (SEQ - 1);
    int t = threadIdx.x;
    #pragma unroll
    for (int p = t; p < 512; p += 256) {
        int h = p >> 5, i = p & 31;
        float2 cs = tab[(s << 5) + i];
        size_t src = (size_t)bs * 3072 + h * 64 + 2 * i;
        size_t dst = ((size_t)(b * NH + h) * SEQ + s) * 64 + 2 * i;
        ushort2 qv = *reinterpret_cast<const ushort2*>(qkv + src);
        float q0 = bf2f(qv.x), q1 = bf2f(qv.y);
        ushort2 qo;
        qo.x = f2bf((q0 * cs.x - q1 * cs.y) * QSCALE);
        qo.y = f2bf((q1 * cs.x + q0 * cs.y) * QSCALE);
        *reinterpret_cast<ushort2*>(Qh + dst) = qo;
        ushort2 kv = *reinterpret_cast<const ushort2*>(qkv + src + 1024);
        float k0 = bf2f(kv.x), k1 = bf2f(kv.y);
        ushort2 ko;
        ko.x = f2bf(k0 * cs.x - k1 * cs.y);
        ko.y = f2bf(k1 * cs.x + k0 * cs.y);
        *reinterpret_cast<ushort2*>(Kh + dst) = ko;
    }
}

// ---------------- V: qkv cols 2048.. -> [B,H,64,S] (tiled transpose) ----------------
__global__ __launch_bounds__(256) void vtrans_kernel(
    const unsigned short* __restrict__ qkv, unsigned short* __restrict__ Vo) {
    __shared__ unsigned short tile[64][65];
    int blk = blockIdx.x;           // (b*NH + h)*32 + st
    int st = blk & 31, bh = blk >> 5;
    int sb = st * 64;
    int t = threadIdx.x;
    int b = bh >> 4, h = bh & 15;
    #pragma unroll
    for (int u = t; u < 1024; u += 256) {
        int sl = u >> 4, d4 = (u & 15) << 2;
        ushort4 v = *reinterpret_cast<const ushort4*>(
            qkv + (size_t)(b * SEQ + sb + sl) * 3072 + 2048 + h * 64 + d4);
        tile[sl][d4] = v.x; tile[sl][d4 + 1] = v.y;
        tile[sl][d4 + 2] = v.z; tile[sl][d4 + 3] = v.w;
    }
    __syncthreads();
    #pragma unroll
    for (int u = t; u < 1024; u += 256) {
        int d = u >> 4, s4 = (u & 15) << 2;
        ushort4 o;
        o.x = tile[s4][d]; o.y = tile[s4 + 1][d];
        o.z = tile[s4 + 2][d]; o.w = tile[s4 + 3][d];
        *reinterpret_cast<ushort4*>(Vo + ((size_t)bh * 64 + d) * SEQ + sb + s4) = o;
    }
}

// ---------------- causal flash attention, KVBLK=64, uniform band pairs --------
// Block (bh, pb) processes band pb then band 63-pb SEQUENTIALLY. Tile counts
// (pb+2)/2 + (65-pb)/2 = 33 for every block -> perfectly uniform grid, no tail.
// 64-wide k-tiles halve all per-tile fixed costs: 16 MFMA + 16 ds_read_b128
// per barrier pair. K/V staged via global_load_lds (linear dest, inverse-
// swizzled source), double-buffered; counted vmcnt(8), vmcnt(0) on last tile.
// Swapped QK^T (mfma(K,Q)); P via per-wave LDS region (stride 72 shorts).
__global__ __launch_bounds__(128) void attn_kernel(
    const unsigned short* __restrict__ Qh, const unsigned short* __restrict__ Kh,
    const unsigned short* __restrict__ Vt, unsigned short* __restrict__ Out) {
    __shared__ unsigned short Kb[2][64 * 64];   // [k][d], chunk-swizzled rows
    __shared__ unsigned short Vb[2][64 * 64];   // [d][k], chunk-swizzled rows
    __shared__ unsigned short Plds[2][16 * 72]; // per-wave P

    const int tid = threadIdx.x;
    const int wid = tid >> 6, lane = tid & 63;
    const int ln15 = lane & 15, g = lane >> 4;
    const int bid = blockIdx.x;
    const int bh = bid & 31;
    const int pb = bid >> 5;                    // 0..31 -> bands {pb, 63-pb}

    const unsigned short* Qp = Qh + (size_t)bh * SEQ * 64;
    const unsigned short* Kp = Kh + (size_t)bh * SEQ * 64;
    const unsigned short* Vp = Vt + (size_t)bh * 64 * SEQ;
    char* Pc = (char*)Plds[wid];

    // --- staging: 512 chunks x 16B per 64x64 tile; 128 threads x 4 chunks ---
    // chunk c: row = c>>3 (k for K, d for V), slot = c&7; swizzle slot^(row&7).
    const unsigned short* kSrc[4];
    const unsigned short* vSrc[4];
    #pragma unroll
    for (int p = 0; p < 4; ++p) {
        int c = tid + (p << 7);
        int row = c >> 3, slot = c & 7;
        kSrc[p] = Kp + (size_t)row * 64 + ((slot ^ (row & 7)) << 3);
        vSrc[p] = Vp + (size_t)row * SEQ + ((slot ^ (row & 7)) << 3);
    }

    auto stage = [&](int kb, int buf) {   // 8 gload_lds per call
        #pragma unroll
        for (int p = 0; p < 4; ++p) {
            unsigned bb = (unsigned)(wid * 1024 + p * 2048);
            gload_lds16(kSrc[p] + (size_t)kb * 64, (char*)Kb[buf] + bb);
            gload_lds16(vSrc[p] + kb, (char*)Vb[buf] + bb);
        }
    };

    // --- compute-side LDS byte offsets (fixed per lane) ---
    unsigned kOff[4][2], vOff[4][2];
    #pragma unroll
    for (int s = 0; s < 4; ++s) {
        int r = ln15 + 16 * s;
        kOff[s][0] = r * 128 + ((g ^ (r & 7)) << 4);
        kOff[s][1] = r * 128 + (((4 + g) ^ (r & 7)) << 4);
    }
    #pragma unroll
    for (int c = 0; c < 4; ++c) {
        int d = c * 16 + ln15;
        vOff[c][0] = d * 128 + ((g ^ (d & 7)) << 4);
        vOff[c][1] = d * 128 + (((4 + g) ^ (d & 7)) << 4);
    }
    const unsigned pW = (unsigned)(ln15 * 144 + 8 * g);   // + 32*s for quarter s
    const unsigned pR = (unsigned)(ln15 * 144 + 16 * g);  // + 64*h for half h

    const int b = bh >> 4, h = bh & 15;

    for (int bi = 0; bi < 2; ++bi) {
        const int bnd = bi ? (63 - pb) : pb;
        const int qb = bnd * 32 + wid * 16;
        const int nt = (bnd + 2) >> 1;          // 64-wide k-tiles
        const int thr = qb + ln15 - 4 * g;      // allowed: kb + 16s + 4g + j <= qb + ln15

        bf16x8 aq0 = *reinterpret_cast<const bf16x8*>(Qp + (size_t)(qb + ln15) * 64 + g * 8);
        bf16x8 aq1 = *reinterpret_cast<const bf16x8*>(Qp + (size_t)(qb + ln15) * 64 + 32 + g * 8);

        f32x4 oacc[4] = {};
        float lsum = 0.f;

        stage(0, 0);   // band prologue

        for (int t = 0; t < nt; ++t) {
            const int kb = t << 6;
            const int cur = t & 1;
            if (t + 1 < nt) {
                stage((t + 1) << 6, cur ^ 1);
                asm volatile("s_waitcnt vmcnt(8)" ::: "memory");  // tile t's 8 done
            } else {
                asm volatile("s_waitcnt vmcnt(0)" ::: "memory");
            }
            __builtin_amdgcn_s_barrier();

            const char* K0 = (const char*)Kb[cur];
            const char* V0 = (const char*)Vb[cur];
            bf16x8 kf[8], bv[8];
            #pragma unroll
            for (int s = 0; s < 4; ++s) {
                kf[2 * s]     = *reinterpret_cast<const bf16x8*>(K0 + kOff[s][0]);
                kf[2 * s + 1] = *reinterpret_cast<const bf16x8*>(K0 + kOff[s][1]);
            }
            #pragma unroll
            for (int c = 0; c < 4; ++c) {
                bv[2 * c]     = *reinterpret_cast<const bf16x8*>(V0 + vOff[c][0]);
                bv[2 * c + 1] = *reinterpret_cast<const bf16x8*>(V0 + vOff[c][1]);
            }

            const f32x4 z = {};
            f32x4 sq[4];
            #pragma unroll
            for (int s = 0; s < 4; ++s) {
                sq[s] = __builtin_amdgcn_mfma_f32_16x16x32_bf16(kf[2 * s], aq0, z, 0, 0, 0);
                sq[s] = __builtin_amdgcn_mfma_f32_16x16x32_bf16(kf[2 * s + 1], aq1, sq[s], 0, 0, 0);
            }

            float pv[4][4];
            if (t == nt - 1) {      // boundary tile: causal mask
                #pragma unroll
                for (int s = 0; s < 4; ++s)
                    #pragma unroll
                    for (int j = 0; j < 4; ++j)
                        pv[s][j] = (j <= thr - kb - 16 * s) ? EXP2(sq[s][j]) : 0.f;
            } else {
                #pragma unroll
                for (int s = 0; s < 4; ++s)
                    #pragma unroll
                    for (int j = 0; j < 4; ++j)
                        pv[s][j] = EXP2(sq[s][j]);
            }
            #pragma unroll
            for (int s = 0; s < 4; ++s)
                lsum += (pv[s][0] + pv[s][1]) + (pv[s][2] + pv[s][3]);

            #pragma unroll
            for (int s = 0; s < 4; ++s) {
                ushort4 w;
                w.x = f2bf(pv[s][0]); w.y = f2bf(pv[s][1]);
                w.z = f2bf(pv[s][2]); w.w = f2bf(pv[s][3]);
                *reinterpret_cast<ushort4*>(Pc + pW + 32 * s) = w;
            }
            asm volatile("s_waitcnt lgkmcnt(0)" ::: "memory");
            bf16x8 ap0 = *reinterpret_cast<const bf16x8*>(Pc + pR);
            bf16x8 ap1 = *reinterpret_cast<const bf16x8*>(Pc + pR + 64);
            #pragma unroll
            for (int c = 0; c < 4; ++c) {
                oacc[c] = __builtin_amdgcn_mfma_f32_16x16x32_bf16(ap0, bv[2 * c], oacc[c], 0, 0, 0);
                oacc[c] = __builtin_amdgcn_mfma_f32_16x16x32_bf16(ap1, bv[2 * c + 1], oacc[c], 0, 0, 0);
            }
            asm volatile("s_waitcnt lgkmcnt(0)" ::: "memory");  // buf[cur] reads done
            __builtin_amdgcn_s_barrier();
        }

        // normalize + store this band
        float r = lsum;
        r += __shfl_xor(r, 16);
        r += __shfl_xor(r, 32);
        float linv = 1.f / r;
        float invj[4];
        #pragma unroll
        for (int j = 0; j < 4; ++j)
            invj[j] = __shfl(linv, 20 * g + j);   // lane with ln15 == 4g+j
        #pragma unroll
        for (int c = 0; c < 4; ++c)
            #pragma unroll
            for (int j = 0; j < 4; ++j) {
                int s = qb + g * 4 + j;
                Out[((size_t)(b * SEQ + s)) * DM + h * 64 + c * 16 + ln15] =
                    f2bf(oacc[c][j] * invj[j]);
            }
    }
}

extern "C" void kernel_launch(void* const* d_in, const int* in_sizes, int n_in,
                              void* d_out, int out_size, void* d_ws, size_t ws_size,
                              hipStream_t stream) {
    const float* x = (const float*)d_in[0];
    const int* pos = (const int*)d_in[1];
    const float* Wq = (const float*)d_in[2];
    const float* Wk = (const float*)d_in[3];
    const float* Wv = (const float*)d_in[4];
    const float* Wo = (const float*)d_in[5];
    float* out = (float*)d_out;

    char* ws = (char*)d_ws;
    const size_t MB = 1024 * 1024;
    unsigned short* xb   = (unsigned short*)(ws + 0 * MB);
    unsigned short* wqkv = (unsigned short*)(ws + 8 * MB);   // wq|wk|wv contiguous
    unsigned short* wob  = (unsigned short*)(ws + 14 * MB);
    unsigned short* qkv  = (unsigned short*)(ws + 16 * MB);  // [4096][3072]
    float2*         tab  = (float2*)       (ws + 40 * MB);   // [2048][32]
    unsigned short* qh   = (unsigned short*)(ws + 41 * MB);
    unsigned short* kh   = (unsigned short*)(ws + 49 * MB);
    unsigned short* vtr  = (unsigned short*)(ws + 57 * MB);
    unsigned short* att  = (unsigned short*)(ws + 65 * MB);

    cvt_all<<<8192, 256, 0, stream>>>(x, Wq, Wk, Wv, Wo, xb, wqkv, wob);
    rope_table<<<256, 256, 0, stream>>>(pos, tab);

    gemm_bt<1><<<dim3(24, 32), 256, 0, stream>>>(xb, wqkv, qkv, 4096, 3072, 1024);

    rope_kernel<<<4096, 256, 0, stream>>>(qkv, tab, qh, kh);
    vtrans_kernel<<<1024, 256, 0, stream>>>(qkv, vtr);

    attn_kernel<<<1024, 128, 0, stream>>>(qh, kh, vtr, att);

    gemm_bt<0><<<dim3(8, 32), 256, 0, stream>>>(att, wob, out, 4096, 1024, 1024);
}

// Round 10
// 126.830 us; speedup vs baseline: 1.0699x; 1.0120x over previous
//
#include <hip/hip_runtime.h>
#include <hip/hip_bf16.h>
#include <cstdint>
#include <cmath>

#define SEQ 2048
#define NH 16
#define DM 1024
#define BATCH 2

typedef short bf16x8 __attribute__((ext_vector_type(8)));
typedef float f32x4 __attribute__((ext_vector_type(4)));
typedef const void __attribute__((address_space(1)))* gas_t;
typedef void __attribute__((address_space(3)))* las_t;

#if __has_builtin(__builtin_amdgcn_exp2f)
#define EXP2(x) __builtin_amdgcn_exp2f(x)
#else
#define EXP2(x) __expf((x) * 0.6931471805599453f)
#endif

// Q prescale: (1/sqrt(64)) * log2(e) so scores are already in log2 domain
#define QSCALE 0.18033688011112042f

static __device__ __forceinline__ unsigned short f2bf(float f) {
    union { __hip_bfloat16 h; unsigned short u; } cv;
    cv.h = __float2bfloat16(f);
    return cv.u;
}
static __device__ __forceinline__ float bf2f(unsigned short u) {
    union { unsigned short u; __hip_bfloat16 h; } cv;
    cv.u = u;
    return __bfloat162float(cv.h);
}

static __device__ __forceinline__ void gload_lds16(const void* g, void* l) {
    __builtin_amdgcn_global_load_lds(
        reinterpret_cast<gas_t>(reinterpret_cast<uintptr_t>(g)),
        reinterpret_cast<las_t>(reinterpret_cast<uintptr_t>(l)),
        16, 0, 0);
}

// ---------------- fp32 -> bf16 convert, all 5 tensors in one launch ----------
__global__ __launch_bounds__(256) void cvt_all(
    const float* __restrict__ x,  const float* __restrict__ wq,
    const float* __restrict__ wk, const float* __restrict__ wv,
    const float* __restrict__ wo,
    unsigned short* __restrict__ xb, unsigned short* __restrict__ wqkv,
    unsigned short* __restrict__ wob) {
    int blk = blockIdx.x;
    const float* src; unsigned short* dst; int base;
    if (blk < 4096)      { src = x;  dst = xb;              base = blk; }
    else if (blk < 5120) { src = wq; dst = wqkv;            base = blk - 4096; }
    else if (blk < 6144) { src = wk; dst = wqkv + 1048576;  base = blk - 5120; }
    else if (blk < 7168) { src = wv; dst = wqkv + 2097152;  base = blk - 6144; }
    else                 { src = wo; dst = wob;             base = blk - 7168; }
    int i = base * 256 + threadIdx.x;
    float4 v = reinterpret_cast<const float4*>(src)[i];
    ushort4 o;
    o.x = f2bf(v.x); o.y = f2bf(v.y); o.z = f2bf(v.z); o.w = f2bf(v.w);
    reinterpret_cast<ushort4*>(dst)[i] = o;
}

// ---------------- 128x128 bf16 GEMM (out-proj): C = A * B^T ----------------
template<int OUT_BF16>
__global__ __launch_bounds__(256) void gemm_bt(
    const unsigned short* __restrict__ A,
    const unsigned short* __restrict__ B,
    void* __restrict__ C, int M, int N, int K) {
    __shared__ unsigned short As[128 * 32];
    __shared__ unsigned short Bs[128 * 32];
    const int tid = threadIdx.x;
    const int lane = tid & 63, wid = tid >> 6;
    const int wr = wid >> 1, wc = wid & 1;
    const int ln15 = lane & 15, kq = lane >> 4;
    const int bm = blockIdx.y, bn = blockIdx.x;

    f32x4 acc[4][4] = {};
    const int nk = K >> 5;
    for (int kt = 0; kt < nk; ++kt) {
        #pragma unroll
        for (int i = 0; i < 2; ++i) {
            int c = i * 256 + tid;
            int row = c >> 2, k8 = (c & 3) << 3;
            size_t gofsA = (size_t)(bm * 128 + row) * K + kt * 32 + k8;
            size_t gofsB = (size_t)(bn * 128 + row) * K + kt * 32 + k8;
            unsigned ldsoff = (unsigned)(i * 256 + wid * 64) * 16;  // wave-uniform
            gload_lds16(A + gofsA, (char*)As + ldsoff);
            gload_lds16(B + gofsB, (char*)Bs + ldsoff);
        }
        __syncthreads();
        bf16x8 af[4], bf[4];
        #pragma unroll
        for (int m = 0; m < 4; ++m)
            af[m] = *reinterpret_cast<const bf16x8*>(&As[(wr * 64 + m * 16 + ln15) * 32 + kq * 8]);
        #pragma unroll
        for (int n = 0; n < 4; ++n)
            bf[n] = *reinterpret_cast<const bf16x8*>(&Bs[(wc * 64 + n * 16 + ln15) * 32 + kq * 8]);
        #pragma unroll
        for (int m = 0; m < 4; ++m)
            #pragma unroll
            for (int n = 0; n < 4; ++n)
                acc[m][n] = __builtin_amdgcn_mfma_f32_16x16x32_bf16(af[m], bf[n], acc[m][n], 0, 0, 0);
        __syncthreads();
    }
    #pragma unroll
    for (int m = 0; m < 4; ++m) {
        #pragma unroll
        for (int n = 0; n < 4; ++n) {
            int col = bn * 128 + wc * 64 + n * 16 + ln15;
            #pragma unroll
            for (int j = 0; j < 4; ++j) {
                int row = bm * 128 + wr * 64 + m * 16 + kq * 4 + j;
                if constexpr (OUT_BF16 != 0)
                    ((unsigned short*)C)[(size_t)row * N + col] = f2bf(acc[m][n][j]);
                else
                    ((float*)C)[(size_t)row * N + col] = acc[m][n][j];
            }
        }
    }
}

// ---------------- 256x256 bf16 GEMM (qkv proj): C = A * B^T, bf16 out --------
// 8 waves (2M x 4N), BK=64, LDS 128 KB double-buffered. Counted vmcnt(8):
// next K-tile's 8 global_load_lds stay in flight across the barrier. 64 MFMA
// + 24 ds_read_b128 per barrier pair. Swizzle: slot ^ (row&7) (16B units),
// pre-swizzled global source + swizzled ds_read (both-sides, m201/m231 rule).
__global__ __launch_bounds__(512) void gemm256_bt(
    const unsigned short* __restrict__ A,
    const unsigned short* __restrict__ B,
    unsigned short* __restrict__ C, int M, int N, int K) {
    __shared__ unsigned short As[2][256 * 64];
    __shared__ unsigned short Bs[2][256 * 64];
    const int tid = threadIdx.x;
    const int lane = tid & 63, wid = tid >> 6;
    const int wm = wid >> 2, wn = wid & 3;          // 2 x 4 waves
    const int ln15 = lane & 15, g = lane >> 4;
    const int bm = blockIdx.y, bn = blockIdx.x;

    // staging sources: chunk c = tid + 512p; row = c>>3, slot = c&7 (16B units)
    const unsigned short* aSrc[4];
    const unsigned short* bSrc[4];
    #pragma unroll
    for (int p = 0; p < 4; ++p) {
        int c = tid + (p << 9);
        int row = c >> 3, slot = c & 7;
        aSrc[p] = A + (size_t)(bm * 256 + row) * K + ((slot ^ (row & 7)) << 3);
        bSrc[p] = B + (size_t)(bn * 256 + row) * K + ((slot ^ (row & 7)) << 3);
    }
    auto stage = [&](int kt, int buf) {   // 8 gload_lds per thread
        #pragma unroll
        for (int p = 0; p < 4; ++p) {
            unsigned dst = (unsigned)(tid + (p << 9)) << 4;  // wave-uniform + lane*16
            gload_lds16(aSrc[p] + kt * 64, (char*)As[buf] + dst);
            gload_lds16(bSrc[p] + kt * 64, (char*)Bs[buf] + dst);
        }
    };

    // compute-side: all frag rows == ln15 (mod 8) -> 2 per-lane slot constants
    const unsigned ps0 = (unsigned)((g ^ (ln15 & 7)) << 4);
    const unsigned ps1 = (unsigned)(((4 + g) ^ (ln15 & 7)) << 4);
    const unsigned aBase = (unsigned)(wm * 128 + ln15) * 128;
    const unsigned bBase = (unsigned)(wn * 64 + ln15) * 128;

    f32x4 acc[8][4] = {};
    const int nkt = K >> 6;

    stage(0, 0);
    stage(1, 1);

    for (int t = 0; t < nkt; ++t) {
        const int cur = t & 1;
        if (t + 1 < nkt) {
            asm volatile("s_waitcnt vmcnt(8)" ::: "memory");   // K-tile t landed
        } else {
            asm volatile("s_waitcnt vmcnt(0)" ::: "memory");
        }
        __builtin_amdgcn_s_barrier();

        const char* Ab = (const char*)As[cur];
        const char* Bb = (const char*)Bs[cur];
        bf16x8 bf[4][2];
        #pragma unroll
        for (int nf = 0; nf < 4; ++nf) {
            bf[nf][0] = *reinterpret_cast<const bf16x8*>(Bb + bBase + nf * 2048 + ps0);
            bf[nf][1] = *reinterpret_cast<const bf16x8*>(Bb + bBase + nf * 2048 + ps1);
        }
        __builtin_amdgcn_s_setprio(1);
        #pragma unroll
        for (int mf = 0; mf < 8; ++mf) {
            bf16x8 af0 = *reinterpret_cast<const bf16x8*>(Ab + aBase + mf * 2048 + ps0);
            bf16x8 af1 = *reinterpret_cast<const bf16x8*>(Ab + aBase + mf * 2048 + ps1);
            #pragma unroll
            for (int nf = 0; nf < 4; ++nf) {
                acc[mf][nf] = __builtin_amdgcn_mfma_f32_16x16x32_bf16(af0, bf[nf][0], acc[mf][nf], 0, 0, 0);
                acc[mf][nf] = __builtin_amdgcn_mfma_f32_16x16x32_bf16(af1, bf[nf][1], acc[mf][nf], 0, 0, 0);
            }
        }
        __builtin_amdgcn_s_setprio(0);
        asm volatile("s_waitcnt lgkmcnt(0)" ::: "memory");  // buf[cur] reads done
        __builtin_amdgcn_s_barrier();
        if (t + 2 < nkt) stage(t + 2, cur);                 // refill freed buffer
    }

    #pragma unroll
    for (int mf = 0; mf < 8; ++mf) {
        #pragma unroll
        for (int nf = 0; nf < 4; ++nf) {
            int col = bn * 256 + wn * 64 + nf * 16 + ln15;
            #pragma unroll
            for (int j = 0; j < 4; ++j) {
                int row = bm * 256 + wm * 128 + mf * 16 + g * 4 + j;
                C[(size_t)row * N + col] = f2bf(acc[mf][nf][j]);
            }
        }
    }
}

// ---------------- RoPE cos/sin table: [S][32] float2 ----------------
__global__ __launch_bounds__(256) void rope_table(const int* __restrict__ pos,
                                                  float2* __restrict__ tab) {
    int idx = blockIdx.x * 256 + threadIdx.x;  // s*32 + i
    int s = idx >> 5, i = idx & 31;
    float fpos = (float)pos[s];
    float freq = exp2f(-(float)i * (13.287712379549449f / 32.0f));  // theta^(-i/32)
    float ang = fpos * freq, sn, cs;
    sincosf(ang, &sn, &cs);
    tab[idx] = make_float2(cs, sn);
}

// ---------------- RoPE + split qkv[B*S][3072] -> Qh,Kh [B,H,S,64] ----------------
__global__ __launch_bounds__(256) void rope_kernel(
    const unsigned short* __restrict__ qkv, const float2* __restrict__ tab,
    unsigned short* __restrict__ Qh, unsigned short* __restrict__ Kh) {
    int bs = blockIdx.x;            // b*SEQ + s
    int b = bs >> 11, s = bs & (SEQ - 1);
    int t = threadIdx.x;
    #pragma unroll
    for (int p = t; p < 512; p += 256) {
        int h = p >> 5, i = p & 31;
        float2 cs = tab[(s << 5) + i];
        size_t src = (size_t)bs * 3072 + h * 64 + 2 * i;
        size_t dst = ((size_t)(b * NH + h) * SEQ + s) * 64 + 2 * i;
        ushort2 qv = *reinterpret_cast<const ushort2*>(qkv + src);
        float q0 = bf2f(qv.x), q1 = bf2f(qv.y);
        ushort2 qo;
        qo.x = f2bf((q0 * cs.x - q1 * cs.y) * QSCALE);
        qo.y = f2bf((q1 * cs.x + q0 * cs.y) * QSCALE);
        *reinterpret_cast<ushort2*>(Qh + dst) = qo;
        ushort2 kv = *reinterpret_cast<const ushort2*>(qkv + src + 1024);
        float k0 = bf2f(kv.x), k1 = bf2f(kv.y);
        ushort2 ko;
        ko.x = f2bf(k0 * cs.x - k1 * cs.y);
        ko.y = f2bf(k1 * cs.x + k0 * cs.y);
        *reinterpret_cast<ushort2*>(Kh + dst) = ko;
    }
}

// ---------------- V: qkv cols 2048.. -> [B,H,64,S] (tiled transpose) ----------------
__global__ __launch_bounds__(256) void vtrans_kernel(
    const unsigned short* __restrict__ qkv, unsigned short* __restrict__ Vo) {
    __shared__ unsigned short tile[64][65];
    int blk = blockIdx.x;           // (b*NH + h)*32 + st
    int st = blk & 31, bh = blk >> 5;
    int sb = st * 64;
    int t = threadIdx.x;
    int b = bh >> 4, h = bh & 15;
    #pragma unroll
    for (int u = t; u < 1024; u += 256) {
        int sl = u >> 4, d4 = (u & 15) << 2;
        ushort4 v = *reinterpret_cast<const ushort4*>(
            qkv + (size_t)(b * SEQ + sb + sl) * 3072 + 2048 + h * 64 + d4);
        tile[sl][d4] = v.x; tile[sl][d4 + 1] = v.y;
        tile[sl][d4 + 2] = v.z; tile[sl][d4 + 3] = v.w;
    }
    __syncthreads();
    #pragma unroll
    for (int u = t; u < 1024; u += 256) {
        int d = u >> 4, s4 = (u & 15) << 2;
        ushort4 o;
        o.x = tile[s4][d]; o.y = tile[s4 + 1][d];
        o.z = tile[s4 + 2][d]; o.w = tile[s4 + 3][d];
        *reinterpret_cast<ushort4*>(Vo + ((size_t)bh * 64 + d) * SEQ + sb + s4) = o;
    }
}

// ---------------- causal flash attention, KVBLK=64, uniform band pairs --------
__global__ __launch_bounds__(128) void attn_kernel(
    const unsigned short* __restrict__ Qh, const unsigned short* __restrict__ Kh,
    const unsigned short* __restrict__ Vt, unsigned short* __restrict__ Out) {
    __shared__ unsigned short Kb[2][64 * 64];   // [k][d], chunk-swizzled rows
    __shared__ unsigned short Vb[2][64 * 64];   // [d][k], chunk-swizzled rows
    __shared__ unsigned short Plds[2][16 * 72]; // per-wave P

    const int tid = threadIdx.x;
    const int wid = tid >> 6, lane = tid & 63;
    const int ln15 = lane & 15, g = lane >> 4;
    const int bid = blockIdx.x;
    const int bh = bid & 31;
    const int pb = bid >> 5;                    // 0..31 -> bands {pb, 63-pb}

    const unsigned short* Qp = Qh + (size_t)bh * SEQ * 64;
    const unsigned short* Kp = Kh + (size_t)bh * SEQ * 64;
    const unsigned short* Vp = Vt + (size_t)bh * 64 * SEQ;
    char* Pc = (char*)Plds[wid];

    const unsigned short* kSrc[4];
    const unsigned short* vSrc[4];
    #pragma unroll
    for (int p = 0; p < 4; ++p) {
        int c = tid + (p << 7);
        int row = c >> 3, slot = c & 7;
        kSrc[p] = Kp + (size_t)row * 64 + ((slot ^ (row & 7)) << 3);
        vSrc[p] = Vp + (size_t)row * SEQ + ((slot ^ (row & 7)) << 3);
    }

    auto stage = [&](int kb, int buf) {   // 8 gload_lds per call
        #pragma unroll
        for (int p = 0; p < 4; ++p) {
            unsigned bb = (unsigned)(wid * 1024 + p * 2048);
            gload_lds16(kSrc[p] + (size_t)kb * 64, (char*)Kb[buf] + bb);
            gload_lds16(vSrc[p] + kb, (char*)Vb[buf] + bb);
        }
    };

    unsigned kOff[4][2], vOff[4][2];
    #pragma unroll
    for (int s = 0; s < 4; ++s) {
        int r = ln15 + 16 * s;
        kOff[s][0] = r * 128 + ((g ^ (r & 7)) << 4);
        kOff[s][1] = r * 128 + (((4 + g) ^ (r & 7)) << 4);
    }
    #pragma unroll
    for (int c = 0; c < 4; ++c) {
        int d = c * 16 + ln15;
        vOff[c][0] = d * 128 + ((g ^ (d & 7)) << 4);
        vOff[c][1] = d * 128 + (((4 + g) ^ (d & 7)) << 4);
    }
    const unsigned pW = (unsigned)(ln15 * 144 + 8 * g);   // + 32*s for quarter s
    const unsigned pR = (unsigned)(ln15 * 144 + 16 * g);  // + 64*h for half h

    const int b = bh >> 4, h = bh & 15;

    for (int bi = 0; bi < 2; ++bi) {
        const int bnd = bi ? (63 - pb) : pb;
        const int qb = bnd * 32 + wid * 16;
        const int nt = (bnd + 2) >> 1;          // 64-wide k-tiles
        const int thr = qb + ln15 - 4 * g;      // allowed: kb + 16s + 4g + j <= qb + ln15

        bf16x8 aq0 = *reinterpret_cast<const bf16x8*>(Qp + (size_t)(qb + ln15) * 64 + g * 8);
        bf16x8 aq1 = *reinterpret_cast<const bf16x8*>(Qp + (size_t)(qb + ln15) * 64 + 32 + g * 8);

        f32x4 oacc[4] = {};
        float lsum = 0.f;

        stage(0, 0);   // band prologue

        for (int t = 0; t < nt; ++t) {
            const int kb = t << 6;
            const int cur = t & 1;
            if (t + 1 < nt) {
                stage((t + 1) << 6, cur ^ 1);
                asm volatile("s_waitcnt vmcnt(8)" ::: "memory");  // tile t's 8 done
            } else {
                asm volatile("s_waitcnt vmcnt(0)" ::: "memory");
            }
            __builtin_amdgcn_s_barrier();

            const char* K0 = (const char*)Kb[cur];
            const char* V0 = (const char*)Vb[cur];
            bf16x8 kf[8], bv[8];
            #pragma unroll
            for (int s = 0; s < 4; ++s) {
                kf[2 * s]     = *reinterpret_cast<const bf16x8*>(K0 + kOff[s][0]);
                kf[2 * s + 1] = *reinterpret_cast<const bf16x8*>(K0 + kOff[s][1]);
            }
            #pragma unroll
            for (int c = 0; c < 4; ++c) {
                bv[2 * c]     = *reinterpret_cast<const bf16x8*>(V0 + vOff[c][0]);
                bv[2 * c + 1] = *reinterpret_cast<const bf16x8*>(V0 + vOff[c][1]);
            }

            const f32x4 z = {};
            f32x4 sq[4];
            #pragma unroll
            for (int s = 0; s < 4; ++s) {
                sq[s] = __builtin_amdgcn_mfma_f32_16x16x32_bf16(kf[2 * s], aq0, z, 0, 0, 0);
                sq[s] = __builtin_amdgcn_mfma_f32_16x16x32_bf16(kf[2 * s + 1], aq1, sq[s], 0, 0, 0);
            }

            float pv[4][4];
            if (t == nt - 1) {      // boundary tile: causal mask
                #pragma unroll
                for (int s = 0; s < 4; ++s)
                    #pragma unroll
                    for (int j = 0; j < 4; ++j)
                        pv[s][j] = (j <= thr - kb - 16 * s) ? EXP2(sq[s][j]) : 0.f;
            } else {
                #pragma unroll
                for (int s = 0; s < 4; ++s)
                    #pragma unroll
                    for (int j = 0; j < 4; ++j)
                        pv[s][j] = EXP2(sq[s][j]);
            }
            #pragma unroll
            for (int s = 0; s < 4; ++s)
                lsum += (pv[s][0] + pv[s][1]) + (pv[s][2] + pv[s][3]);

            #pragma unroll
            for (int s = 0; s < 4; ++s) {
                ushort4 w;
                w.x = f2bf(pv[s][0]); w.y = f2bf(pv[s][1]);
                w.z = f2bf(pv[s][2]); w.w = f2bf(pv[s][3]);
                *reinterpret_cast<ushort4*>(Pc + pW + 32 * s) = w;
            }
            asm volatile("s_waitcnt lgkmcnt(0)" ::: "memory");
            bf16x8 ap0 = *reinterpret_cast<const bf16x8*>(Pc + pR);
            bf16x8 ap1 = *reinterpret_cast<const bf16x8*>(Pc + pR + 64);
            #pragma unroll
            for (int c = 0; c < 4; ++c) {
                oacc[c] = __builtin_amdgcn_mfma_f32_16x16x32_bf16(ap0, bv[2 * c], oacc[c], 0, 0, 0);
                oacc[c] = __builtin_amdgcn_mfma_f32_16x16x32_bf16(ap1, bv[2 * c + 1], oacc[c], 0, 0, 0);
            }
            asm volatile("s_waitcnt lgkmcnt(0)" ::: "memory");  // buf[cur] reads done
            __builtin_amdgcn_s_barrier();
        }

        // normalize + store this band
        float r = lsum;
        r += __shfl_xor(r, 16);
        r += __shfl_xor(r, 32);
        float linv = 1.f / r;
        float invj[4];
        #pragma unroll
        for (int j = 0; j < 4; ++j)
            invj[j] = __shfl(linv, 20 * g + j);   // lane with ln15 == 4g+j
        #pragma unroll
        for (int c = 0; c < 4; ++c)
            #pragma unroll
            for (int j = 0; j < 4; ++j) {
                int s = qb + g * 4 + j;
                Out[((size_t)(b * SEQ + s)) * DM + h * 64 + c * 16 + ln15] =
                    f2bf(oacc[c][j] * invj[j]);
            }
    }
}

extern "C" void kernel_launch(void* const* d_in, const int* in_sizes, int n_in,
                              void* d_out, int out_size, void* d_ws, size_t ws_size,
                              hipStream_t stream) {
    const float* x = (const float*)d_in[0];
    const int* pos = (const int*)d_in[1];
    const float* Wq = (const float*)d_in[2];
    const float* Wk = (const float*)d_in[3];
    const float* Wv = (const float*)d_in[4];
    const float* Wo = (const float*)d_in[5];
    float* out = (float*)d_out;

    char* ws = (char*)d_ws;
    const size_t MB = 1024 * 1024;
    unsigned short* xb   = (unsigned short*)(ws + 0 * MB);
    unsigned short* wqkv = (unsigned short*)(ws + 8 * MB);   // wq|wk|wv contiguous
    unsigned short* wob  = (unsigned short*)(ws + 14 * MB);
    unsigned short* qkv  = (unsigned short*)(ws + 16 * MB);  // [4096][3072]
    float2*         tab  = (float2*)       (ws + 40 * MB);   // [2048][32]
    unsigned short* qh   = (unsigned short*)(ws + 41 * MB);
    unsigned short* kh   = (unsigned short*)(ws + 49 * MB);
    unsigned short* vtr  = (unsigned short*)(ws + 57 * MB);
    unsigned short* att  = (unsigned short*)(ws + 65 * MB);

    cvt_all<<<8192, 256, 0, stream>>>(x, Wq, Wk, Wv, Wo, xb, wqkv, wob);
    rope_table<<<256, 256, 0, stream>>>(pos, tab);

    gemm256_bt<<<dim3(12, 16), 512, 0, stream>>>(xb, wqkv, qkv, 4096, 3072, 1024);

    rope_kernel<<<4096, 256, 0, stream>>>(qkv, tab, qh, kh);
    vtrans_kernel<<<1024, 256, 0, stream>>>(qkv, vtr);

    attn_kernel<<<1024, 128, 0, stream>>>(qh, kh, vtr, att);

    gemm_bt<0><<<dim3(8, 32), 256, 0, stream>>>(att, wob, out, 4096, 1024, 1024);
}

// Round 11
// 124.147 us; speedup vs baseline: 1.0930x; 1.0216x over previous
//
#include <hip/hip_runtime.h>
#include <hip/hip_bf16.h>
#include <cstdint>
#include <cmath>

#define SEQ 2048
#define NH 16
#define DM 1024
#define BATCH 2

typedef short bf16x8 __attribute__((ext_vector_type(8)));
typedef float f32x4 __attribute__((ext_vector_type(4)));
typedef const void __attribute__((address_space(1)))* gas_t;
typedef void __attribute__((address_space(3)))* las_t;

#if __has_builtin(__builtin_amdgcn_exp2f)
#define EXP2(x) __builtin_amdgcn_exp2f(x)
#else
#define EXP2(x) __expf((x) * 0.6931471805599453f)
#endif

// Q prescale: (1/sqrt(64)) * log2(e) so scores are already in log2 domain
#define QSCALE 0.18033688011112042f

static __device__ __forceinline__ unsigned short f2bf(float f) {
    union { __hip_bfloat16 h; unsigned short u; } cv;
    cv.h = __float2bfloat16(f);
    return cv.u;
}
static __device__ __forceinline__ float bf2f(unsigned short u) {
    union { unsigned short u; __hip_bfloat16 h; } cv;
    cv.u = u;
    return __bfloat162float(cv.h);
}

static __device__ __forceinline__ void gload_lds16(const void* g, void* l) {
    __builtin_amdgcn_global_load_lds(
        reinterpret_cast<gas_t>(reinterpret_cast<uintptr_t>(g)),
        reinterpret_cast<las_t>(reinterpret_cast<uintptr_t>(l)),
        16, 0, 0);
}

// ---------------- fp32 -> bf16 convert, all 5 tensors in one launch ----------
__global__ __launch_bounds__(256) void cvt_all(
    const float* __restrict__ x,  const float* __restrict__ wq,
    const float* __restrict__ wk, const float* __restrict__ wv,
    const float* __restrict__ wo,
    unsigned short* __restrict__ xb, unsigned short* __restrict__ wqkv,
    unsigned short* __restrict__ wob) {
    int blk = blockIdx.x;
    const float* src; unsigned short* dst; int base;
    if (blk < 4096)      { src = x;  dst = xb;              base = blk; }
    else if (blk < 5120) { src = wq; dst = wqkv;            base = blk - 4096; }
    else if (blk < 6144) { src = wk; dst = wqkv + 1048576;  base = blk - 5120; }
    else if (blk < 7168) { src = wv; dst = wqkv + 2097152;  base = blk - 6144; }
    else                 { src = wo; dst = wob;             base = blk - 7168; }
    int i = base * 256 + threadIdx.x;
    float4 v = reinterpret_cast<const float4*>(src)[i];
    ushort4 o;
    o.x = f2bf(v.x); o.y = f2bf(v.y); o.z = f2bf(v.z); o.w = f2bf(v.w);
    reinterpret_cast<ushort4*>(dst)[i] = o;
}

// ---------------- 128x128 bf16 GEMM (out-proj): C = A * B^T ----------------
template<int OUT_BF16>
__global__ __launch_bounds__(256) void gemm_bt(
    const unsigned short* __restrict__ A,
    const unsigned short* __restrict__ B,
    void* __restrict__ C, int M, int N, int K) {
    __shared__ unsigned short As[128 * 32];
    __shared__ unsigned short Bs[128 * 32];
    const int tid = threadIdx.x;
    const int lane = tid & 63, wid = tid >> 6;
    const int wr = wid >> 1, wc = wid & 1;
    const int ln15 = lane & 15, kq = lane >> 4;
    const int bm = blockIdx.y, bn = blockIdx.x;

    f32x4 acc[4][4] = {};
    const int nk = K >> 5;
    for (int kt = 0; kt < nk; ++kt) {
        #pragma unroll
        for (int i = 0; i < 2; ++i) {
            int c = i * 256 + tid;
            int row = c >> 2, k8 = (c & 3) << 3;
            size_t gofsA = (size_t)(bm * 128 + row) * K + kt * 32 + k8;
            size_t gofsB = (size_t)(bn * 128 + row) * K + kt * 32 + k8;
            unsigned ldsoff = (unsigned)(i * 256 + wid * 64) * 16;  // wave-uniform
            gload_lds16(A + gofsA, (char*)As + ldsoff);
            gload_lds16(B + gofsB, (char*)Bs + ldsoff);
        }
        __syncthreads();
        bf16x8 af[4], bf[4];
        #pragma unroll
        for (int m = 0; m < 4; ++m)
            af[m] = *reinterpret_cast<const bf16x8*>(&As[(wr * 64 + m * 16 + ln15) * 32 + kq * 8]);
        #pragma unroll
        for (int n = 0; n < 4; ++n)
            bf[n] = *reinterpret_cast<const bf16x8*>(&Bs[(wc * 64 + n * 16 + ln15) * 32 + kq * 8]);
        #pragma unroll
        for (int m = 0; m < 4; ++m)
            #pragma unroll
            for (int n = 0; n < 4; ++n)
                acc[m][n] = __builtin_amdgcn_mfma_f32_16x16x32_bf16(af[m], bf[n], acc[m][n], 0, 0, 0);
        __syncthreads();
    }
    #pragma unroll
    for (int m = 0; m < 4; ++m) {
        #pragma unroll
        for (int n = 0; n < 4; ++n) {
            int col = bn * 128 + wc * 64 + n * 16 + ln15;
            #pragma unroll
            for (int j = 0; j < 4; ++j) {
                int row = bm * 128 + wr * 64 + m * 16 + kq * 4 + j;
                if constexpr (OUT_BF16 != 0)
                    ((unsigned short*)C)[(size_t)row * N + col] = f2bf(acc[m][n][j]);
                else
                    ((float*)C)[(size_t)row * N + col] = acc[m][n][j];
            }
        }
    }
}

// ---------------- 256x256 bf16 GEMM (qkv proj), 8-phase schedule -------------
// m201-style: 8 waves (2M x 4N), BK=64, 2 K-tiles per iteration, 8 phases.
// Each phase: {ds_read subtile || stage 1 half-tile (2 gload_lds)} -> barrier
// -> lgkmcnt(0) -> setprio(1) + 16 MFMA + setprio(0) -> barrier.
// Staging windows (derived from buffer free times): ph1,2: A(t1)->buf1;
// ph3,4: B(t0+2)->buf0; ph5,6: A(t0+2)->buf0; ph7,8: B(t1+2)->buf1.
// vmcnt(4) only at phases 4 and 8 (forces 2 oldest half-tiles; 2 stay in
// flight). vmcnt(0) variant on the last iteration (stages skipped there).
__global__ __launch_bounds__(512) void gemm256_bt(
    const unsigned short* __restrict__ A,
    const unsigned short* __restrict__ B,
    unsigned short* __restrict__ C, int M, int N, int K) {
    __shared__ unsigned short As[2][256 * 64];
    __shared__ unsigned short Bs[2][256 * 64];
    const int tid = threadIdx.x;
    const int lane = tid & 63, wid = tid >> 6;
    const int wm = wid >> 2, wn = wid & 3;          // 2 x 4 waves
    const int ln15 = lane & 15, g = lane >> 4;
    const int bm = blockIdx.y, bn = blockIdx.x;

    // staging sources: chunk c = tid + 512p; row = c>>3 = 64p + (tid>>3),
    // slot = c&7 = tid&7 (16B units). Half h of a tile = p in {2h, 2h+1}.
    const unsigned short* aSrc[4];
    const unsigned short* bSrc[4];
    #pragma unroll
    for (int p = 0; p < 4; ++p) {
        int c = tid + (p << 9);
        int row = c >> 3, slot = c & 7;
        aSrc[p] = A + (size_t)(bm * 256 + row) * K + ((slot ^ (row & 7)) << 3);
        bSrc[p] = B + (size_t)(bn * 256 + row) * K + ((slot ^ (row & 7)) << 3);
    }
    auto stageA = [&](int kt, int h) {   // one half-tile = 2 gload_lds / thread
        #pragma unroll
        for (int p = 2 * h; p < 2 * h + 2; ++p) {
            unsigned dst = (unsigned)(tid + (p << 9)) << 4;
            gload_lds16(aSrc[p] + kt * 64, (char*)As[kt & 1] + dst);
        }
    };
    auto stageB = [&](int kt, int h) {
        #pragma unroll
        for (int p = 2 * h; p < 2 * h + 2; ++p) {
            unsigned dst = (unsigned)(tid + (p << 9)) << 4;
            gload_lds16(bSrc[p] + kt * 64, (char*)Bs[kt & 1] + dst);
        }
    };

    // compute-side: all frag rows == ln15 (mod 8) -> 2 per-lane slot constants
    const unsigned ps0 = (unsigned)((g ^ (ln15 & 7)) << 4);
    const unsigned ps1 = (unsigned)(((4 + g) ^ (ln15 & 7)) << 4);
    const unsigned aBase = (unsigned)(wm * 128 + ln15) * 128;
    const unsigned bBase = (unsigned)(wn * 64 + ln15) * 128;

    f32x4 acc[8][4] = {};
    const int nkt = K >> 6;          // 16 K-tiles
    const int nit = nkt >> 1;        // 8 iterations

    // prologue: A(0), B(0) -> buf0; B(1) -> buf1; full drain once.
    stageA(0, 0); stageA(0, 1);
    stageB(0, 0); stageB(0, 1);
    stageB(1, 0); stageB(1, 1);
    asm volatile("s_waitcnt vmcnt(0)" ::: "memory");
    __builtin_amdgcn_s_barrier();

    for (int j = 0; j < nit; ++j) {
        const int t0 = 2 * j, t1 = 2 * j + 1;
        const bool more = (t0 + 2) < nkt;
        #pragma unroll
        for (int grp = 0; grp < 2; ++grp) {          // grp0: tile t0 (buf0), grp1: t1 (buf1)
            const char* Ab = (const char*)As[grp];
            const char* Bb = (const char*)Bs[grp];
            bf16x8 bfr[4][2];
            #pragma unroll
            for (int q = 0; q < 4; ++q) {            // 4 phases per tile
                if (q == 0) {
                    #pragma unroll
                    for (int nf = 0; nf < 4; ++nf) {
                        bfr[nf][0] = *reinterpret_cast<const bf16x8*>(Bb + bBase + nf * 2048 + ps0);
                        bfr[nf][1] = *reinterpret_cast<const bf16x8*>(Bb + bBase + nf * 2048 + ps1);
                    }
                }
                bf16x8 af0 = *reinterpret_cast<const bf16x8*>(Ab + aBase + (2 * q) * 2048 + ps0);
                bf16x8 af1 = *reinterpret_cast<const bf16x8*>(Ab + aBase + (2 * q) * 2048 + ps1);
                bf16x8 af2 = *reinterpret_cast<const bf16x8*>(Ab + aBase + (2 * q + 1) * 2048 + ps0);
                bf16x8 af3 = *reinterpret_cast<const bf16x8*>(Ab + aBase + (2 * q + 1) * 2048 + ps1);

                // ---- staging schedule ----
                if (grp == 0) {
                    if (q == 0) stageA(t1, 0);
                    else if (q == 1) stageA(t1, 1);
                    else if (q == 2) { if (more) stageB(t0 + 2, 0); }
                    else {
                        if (more) { stageB(t0 + 2, 1);
                                    asm volatile("s_waitcnt vmcnt(4)" ::: "memory"); }
                        else      { asm volatile("s_waitcnt vmcnt(0)" ::: "memory"); }
                    }
                } else {
                    if (q == 0)      { if (more) stageA(t0 + 2, 0); }
                    else if (q == 1) { if (more) stageA(t0 + 2, 1); }
                    else if (q == 2) { if (more) stageB(t1 + 2, 0); }
                    else {
                        if (more) { stageB(t1 + 2, 1);
                                    asm volatile("s_waitcnt vmcnt(4)" ::: "memory"); }
                        else      { asm volatile("s_waitcnt vmcnt(0)" ::: "memory"); }
                    }
                }

                __builtin_amdgcn_s_barrier();
                asm volatile("s_waitcnt lgkmcnt(0)" ::: "memory");
                __builtin_amdgcn_s_setprio(1);
                #pragma unroll
                for (int nf = 0; nf < 4; ++nf) {
                    acc[2 * q][nf] = __builtin_amdgcn_mfma_f32_16x16x32_bf16(af0, bfr[nf][0], acc[2 * q][nf], 0, 0, 0);
                    acc[2 * q][nf] = __builtin_amdgcn_mfma_f32_16x16x32_bf16(af1, bfr[nf][1], acc[2 * q][nf], 0, 0, 0);
                    acc[2 * q + 1][nf] = __builtin_amdgcn_mfma_f32_16x16x32_bf16(af2, bfr[nf][0], acc[2 * q + 1][nf], 0, 0, 0);
                    acc[2 * q + 1][nf] = __builtin_amdgcn_mfma_f32_16x16x32_bf16(af3, bfr[nf][1], acc[2 * q + 1][nf], 0, 0, 0);
                }
                __builtin_amdgcn_s_setprio(0);
                __builtin_amdgcn_s_barrier();
            }
        }
    }

    #pragma unroll
    for (int mf = 0; mf < 8; ++mf) {
        #pragma unroll
        for (int nf = 0; nf < 4; ++nf) {
            int col = bn * 256 + wn * 64 + nf * 16 + ln15;
            #pragma unroll
            for (int j = 0; j < 4; ++j) {
                int row = bm * 256 + wm * 128 + mf * 16 + g * 4 + j;
                C[(size_t)row * N + col] = f2bf(acc[mf][nf][j]);
            }
        }
    }
}

// ---------------- RoPE cos/sin table: [S][32] float2 ----------------
__global__ __launch_bounds__(256) void rope_table(const int* __restrict__ pos,
                                                  float2* __restrict__ tab) {
    int idx = blockIdx.x * 256 + threadIdx.x;  // s*32 + i
    int s = idx >> 5, i = idx & 31;
    float fpos = (float)pos[s];
    float freq = exp2f(-(float)i * (13.287712379549449f / 32.0f));  // theta^(-i/32)
    float ang = fpos * freq, sn, cs;
    sincosf(ang, &sn, &cs);
    tab[idx] = make_float2(cs, sn);
}

// ---------------- RoPE + split qkv[B*S][3072] -> Qh,Kh [B,H,S,64] ----------------
__global__ __launch_bounds__(256) void rope_kernel(
    const unsigned short* __restrict__ qkv, const float2* __restrict__ tab,
    unsigned short* __restrict__ Qh, unsigned short* __restrict__ Kh) {
    int bs = blockIdx.x;            // b*SEQ + s
    int b = bs >> 11, s = bs & (SEQ - 1);
    int t = threadIdx.x;
    #pragma unroll
    for (int p = t; p < 512; p += 256) {
        int h = p >> 5, i = p & 31;
        float2 cs = tab[(s << 5) + i];
        size_t src = (size_t)bs * 3072 + h * 64 + 2 * i;
        size_t dst = ((size_t)(b * NH + h) * SEQ + s) * 64 + 2 * i;
        ushort2 qv = *reinterpret_cast<const ushort2*>(qkv + src);
        float q0 = bf2f(qv.x), q1 = bf2f(qv.y);
        ushort2 qo;
        qo.x = f2bf((q0 * cs.x - q1 * cs.y) * QSCALE);
        qo.y = f2bf((q1 * cs.x + q0 * cs.y) * QSCALE);
        *reinterpret_cast<ushort2*>(Qh + dst) = qo;
        ushort2 kv = *reinterpret_cast<const ushort2*>(qkv + src + 1024);
        float k0 = bf2f(kv.x), k1 = bf2f(kv.y);
        ushort2 ko;
        ko.x = f2bf(k0 * cs.x - k1 * cs.y);
        ko.y = f2bf(k1 * cs.x + k0 * cs.y);
        *reinterpret_cast<ushort2*>(Kh + dst) = ko;
    }
}

// ---------------- V: qkv cols 2048.. -> [B,H,64,S] (tiled transpose) ----------------
__global__ __launch_bounds__(256) void vtrans_kernel(
    const unsigned short* __restrict__ qkv, unsigned short* __restrict__ Vo) {
    __shared__ unsigned short tile[64][65];
    int blk = blockIdx.x;           // (b*NH + h)*32 + st
    int st = blk & 31, bh = blk >> 5;
    int sb = st * 64;
    int t = threadIdx.x;
    int b = bh >> 4, h = bh & 15;
    #pragma unroll
    for (int u = t; u < 1024; u += 256) {
        int sl = u >> 4, d4 = (u & 15) << 2;
        ushort4 v = *reinterpret_cast<const ushort4*>(
            qkv + (size_t)(b * SEQ + sb + sl) * 3072 + 2048 + h * 64 + d4);
        tile[sl][d4] = v.x; tile[sl][d4 + 1] = v.y;
        tile[sl][d4 + 2] = v.z; tile[sl][d4 + 3] = v.w;
    }
    __syncthreads();
    #pragma unroll
    for (int u = t; u < 1024; u += 256) {
        int d = u >> 4, s4 = (u & 15) << 2;
        ushort4 o;
        o.x = tile[s4][d]; o.y = tile[s4 + 1][d];
        o.z = tile[s4 + 2][d]; o.w = tile[s4 + 3][d];
        *reinterpret_cast<ushort4*>(Vo + ((size_t)bh * 64 + d) * SEQ + sb + s4) = o;
    }
}

// ---------------- causal flash attention, KVBLK=64, uniform band pairs --------
__global__ __launch_bounds__(128) void attn_kernel(
    const unsigned short* __restrict__ Qh, const unsigned short* __restrict__ Kh,
    const unsigned short* __restrict__ Vt, unsigned short* __restrict__ Out) {
    __shared__ unsigned short Kb[2][64 * 64];   // [k][d], chunk-swizzled rows
    __shared__ unsigned short Vb[2][64 * 64];   // [d][k], chunk-swizzled rows
    __shared__ unsigned short Plds[2][16 * 72]; // per-wave P

    const int tid = threadIdx.x;
    const int wid = tid >> 6, lane = tid & 63;
    const int ln15 = lane & 15, g = lane >> 4;
    const int bid = blockIdx.x;
    const int bh = bid & 31;
    const int pb = bid >> 5;                    // 0..31 -> bands {pb, 63-pb}

    const unsigned short* Qp = Qh + (size_t)bh * SEQ * 64;
    const unsigned short* Kp = Kh + (size_t)bh * SEQ * 64;
    const unsigned short* Vp = Vt + (size_t)bh * 64 * SEQ;
    char* Pc = (char*)Plds[wid];

    const unsigned short* kSrc[4];
    const unsigned short* vSrc[4];
    #pragma unroll
    for (int p = 0; p < 4; ++p) {
        int c = tid + (p << 7);
        int row = c >> 3, slot = c & 7;
        kSrc[p] = Kp + (size_t)row * 64 + ((slot ^ (row & 7)) << 3);
        vSrc[p] = Vp + (size_t)row * SEQ + ((slot ^ (row & 7)) << 3);
    }

    auto stage = [&](int kb, int buf) {   // 8 gload_lds per call
        #pragma unroll
        for (int p = 0; p < 4; ++p) {
            unsigned bb = (unsigned)(wid * 1024 + p * 2048);
            gload_lds16(kSrc[p] + (size_t)kb * 64, (char*)Kb[buf] + bb);
            gload_lds16(vSrc[p] + kb, (char*)Vb[buf] + bb);
        }
    };

    unsigned kOff[4][2], vOff[4][2];
    #pragma unroll
    for (int s = 0; s < 4; ++s) {
        int r = ln15 + 16 * s;
        kOff[s][0] = r * 128 + ((g ^ (r & 7)) << 4);
        kOff[s][1] = r * 128 + (((4 + g) ^ (r & 7)) << 4);
    }
    #pragma unroll
    for (int c = 0; c < 4; ++c) {
        int d = c * 16 + ln15;
        vOff[c][0] = d * 128 + ((g ^ (d & 7)) << 4);
        vOff[c][1] = d * 128 + (((4 + g) ^ (d & 7)) << 4);
    }
    const unsigned pW = (unsigned)(ln15 * 144 + 8 * g);   // + 32*s for quarter s
    const unsigned pR = (unsigned)(ln15 * 144 + 16 * g);  // + 64*h for half h

    const int b = bh >> 4, h = bh & 15;

    for (int bi = 0; bi < 2; ++bi) {
        const int bnd = bi ? (63 - pb) : pb;
        const int qb = bnd * 32 + wid * 16;
        const int nt = (bnd + 2) >> 1;          // 64-wide k-tiles
        const int thr = qb + ln15 - 4 * g;      // allowed: kb + 16s + 4g + j <= qb + ln15

        bf16x8 aq0 = *reinterpret_cast<const bf16x8*>(Qp + (size_t)(qb + ln15) * 64 + g * 8);
        bf16x8 aq1 = *reinterpret_cast<const bf16x8*>(Qp + (size_t)(qb + ln15) * 64 + 32 + g * 8);

        f32x4 oacc[4] = {};
        float lsum = 0.f;

        stage(0, 0);   // band prologue

        for (int t = 0; t < nt; ++t) {
            const int kb = t << 6;
            const int cur = t & 1;
            if (t + 1 < nt) {
                stage((t + 1) << 6, cur ^ 1);
                asm volatile("s_waitcnt vmcnt(8)" ::: "memory");  // tile t's 8 done
            } else {
                asm volatile("s_waitcnt vmcnt(0)" ::: "memory");
            }
            __builtin_amdgcn_s_barrier();

            const char* K0 = (const char*)Kb[cur];
            const char* V0 = (const char*)Vb[cur];
            bf16x8 kf[8], bv[8];
            #pragma unroll
            for (int s = 0; s < 4; ++s) {
                kf[2 * s]     = *reinterpret_cast<const bf16x8*>(K0 + kOff[s][0]);
                kf[2 * s + 1] = *reinterpret_cast<const bf16x8*>(K0 + kOff[s][1]);
            }
            #pragma unroll
            for (int c = 0; c < 4; ++c) {
                bv[2 * c]     = *reinterpret_cast<const bf16x8*>(V0 + vOff[c][0]);
                bv[2 * c + 1] = *reinterpret_cast<const bf16x8*>(V0 + vOff[c][1]);
            }

            const f32x4 z = {};
            f32x4 sq[4];
            #pragma unroll
            for (int s = 0; s < 4; ++s) {
                sq[s] = __builtin_amdgcn_mfma_f32_16x16x32_bf16(kf[2 * s], aq0, z, 0, 0, 0);
                sq[s] = __builtin_amdgcn_mfma_f32_16x16x32_bf16(kf[2 * s + 1], aq1, sq[s], 0, 0, 0);
            }

            float pv[4][4];
            if (t == nt - 1) {      // boundary tile: causal mask
                #pragma unroll
                for (int s = 0; s < 4; ++s)
                    #pragma unroll
                    for (int j = 0; j < 4; ++j)
                        pv[s][j] = (j <= thr - kb - 16 * s) ? EXP2(sq[s][j]) : 0.f;
            } else {
                #pragma unroll
                for (int s = 0; s < 4; ++s)
                    #pragma unroll
                    for (int j = 0; j < 4; ++j)
                        pv[s][j] = EXP2(sq[s][j]);
            }
            #pragma unroll
            for (int s = 0; s < 4; ++s)
                lsum += (pv[s][0] + pv[s][1]) + (pv[s][2] + pv[s][3]);

            #pragma unroll
            for (int s = 0; s < 4; ++s) {
                ushort4 w;
                w.x = f2bf(pv[s][0]); w.y = f2bf(pv[s][1]);
                w.z = f2bf(pv[s][2]); w.w = f2bf(pv[s][3]);
                *reinterpret_cast<ushort4*>(Pc + pW + 32 * s) = w;
            }
            asm volatile("s_waitcnt lgkmcnt(0)" ::: "memory");
            bf16x8 ap0 = *reinterpret_cast<const bf16x8*>(Pc + pR);
            bf16x8 ap1 = *reinterpret_cast<const bf16x8*>(Pc + pR + 64);
            #pragma unroll
            for (int c = 0; c < 4; ++c) {
                oacc[c] = __builtin_amdgcn_mfma_f32_16x16x32_bf16(ap0, bv[2 * c], oacc[c], 0, 0, 0);
                oacc[c] = __builtin_amdgcn_mfma_f32_16x16x32_bf16(ap1, bv[2 * c + 1], oacc[c], 0, 0, 0);
            }
            asm volatile("s_waitcnt lgkmcnt(0)" ::: "memory");  // buf[cur] reads done
            __builtin_amdgcn_s_barrier();
        }

        // normalize + store this band
        float r = lsum;
        r += __shfl_xor(r, 16);
        r += __shfl_xor(r, 32);
        float linv = 1.f / r;
        float invj[4];
        #pragma unroll
        for (int j = 0; j < 4; ++j)
            invj[j] = __shfl(linv, 20 * g + j);   // lane with ln15 == 4g+j
        #pragma unroll
        for (int c = 0; c < 4; ++c)
            #pragma unroll
            for (int j = 0; j < 4; ++j) {
                int s = qb + g * 4 + j;
                Out[((size_t)(b * SEQ + s)) * DM + h * 64 + c * 16 + ln15] =
                    f2bf(oacc[c][j] * invj[j]);
            }
    }
}

extern "C" void kernel_launch(void* const* d_in, const int* in_sizes, int n_in,
                              void* d_out, int out_size, void* d_ws, size_t ws_size,
                              hipStream_t stream) {
    const float* x = (const float*)d_in[0];
    const int* pos = (const int*)d_in[1];
    const float* Wq = (const float*)d_in[2];
    const float* Wk = (const float*)d_in[3];
    const float* Wv = (const float*)d_in[4];
    const float* Wo = (const float*)d_in[5];
    float* out = (float*)d_out;

    char* ws = (char*)d_ws;
    const size_t MB = 1024 * 1024;
    unsigned short* xb   = (unsigned short*)(ws + 0 * MB);
    unsigned short* wqkv = (unsigned short*)(ws + 8 * MB);   // wq|wk|wv contiguous
    unsigned short* wob  = (unsigned short*)(ws + 14 * MB);
    unsigned short* qkv  = (unsigned short*)(ws + 16 * MB);  // [4096][3072]
    float2*         tab  = (float2*)       (ws + 40 * MB);   // [2048][32]
    unsigned short* qh   = (unsigned short*)(ws + 41 * MB);
    unsigned short* kh   = (unsigned short*)(ws + 49 * MB);
    unsigned short* vtr  = (unsigned short*)(ws + 57 * MB);
    unsigned short* att  = (unsigned short*)(ws + 65 * MB);

    cvt_all<<<8192, 256, 0, stream>>>(x, Wq, Wk, Wv, Wo, xb, wqkv, wob);
    rope_table<<<256, 256, 0, stream>>>(pos, tab);

    gemm256_bt<<<dim3(12, 16), 512, 0, stream>>>(xb, wqkv, qkv, 4096, 3072, 1024);

    rope_kernel<<<4096, 256, 0, stream>>>(qkv, tab, qh, kh);
    vtrans_kernel<<<1024, 256, 0, stream>>>(qkv, vtr);

    attn_kernel<<<1024, 128, 0, stream>>>(qh, kh, vtr, att);

    gemm_bt<0><<<dim3(8, 32), 256, 0, stream>>>(att, wob, out, 4096, 1024, 1024);
}

// Round 12
// 119.807 us; speedup vs baseline: 1.1326x; 1.0362x over previous
//
#include <hip/hip_runtime.h>
#include <hip/hip_bf16.h>
#include <cstdint>
#include <cmath>

#define SEQ 2048
#define NH 16
#define DM 1024
#define BATCH 2

typedef short bf16x8 __attribute__((ext_vector_type(8)));
typedef float f32x4 __attribute__((ext_vector_type(4)));
typedef const void __attribute__((address_space(1)))* gas_t;
typedef void __attribute__((address_space(3)))* las_t;

#if __has_builtin(__builtin_amdgcn_exp2f)
#define EXP2(x) __builtin_amdgcn_exp2f(x)
#else
#define EXP2(x) __expf((x) * 0.6931471805599453f)
#endif

// Q prescale: (1/sqrt(64)) * log2(e) so scores are already in log2 domain
#define QSCALE 0.18033688011112042f

static __device__ __forceinline__ unsigned short f2bf(float f) {
    union { __hip_bfloat16 h; unsigned short u; } cv;
    cv.h = __float2bfloat16(f);
    return cv.u;
}
static __device__ __forceinline__ float bf2f(unsigned short u) {
    union { unsigned short u; __hip_bfloat16 h; } cv;
    cv.u = u;
    return __bfloat162float(cv.h);
}

static __device__ __forceinline__ void gload_lds16(const void* g, void* l) {
    __builtin_amdgcn_global_load_lds(
        reinterpret_cast<gas_t>(reinterpret_cast<uintptr_t>(g)),
        reinterpret_cast<las_t>(reinterpret_cast<uintptr_t>(l)),
        16, 0, 0);
}

// ---------------- fp32 -> bf16 convert, all 5 tensors in one launch ----------
__global__ __launch_bounds__(256) void cvt_all(
    const float* __restrict__ x,  const float* __restrict__ wq,
    const float* __restrict__ wk, const float* __restrict__ wv,
    const float* __restrict__ wo,
    unsigned short* __restrict__ xb, unsigned short* __restrict__ wqkv,
    unsigned short* __restrict__ wob) {
    int blk = blockIdx.x;
    const float* src; unsigned short* dst; int base;
    if (blk < 4096)      { src = x;  dst = xb;              base = blk; }
    else if (blk < 5120) { src = wq; dst = wqkv;            base = blk - 4096; }
    else if (blk < 6144) { src = wk; dst = wqkv + 1048576;  base = blk - 5120; }
    else if (blk < 7168) { src = wv; dst = wqkv + 2097152;  base = blk - 6144; }
    else                 { src = wo; dst = wob;             base = blk - 7168; }
    int i = base * 256 + threadIdx.x;
    float4 v = reinterpret_cast<const float4*>(src)[i];
    ushort4 o;
    o.x = f2bf(v.x); o.y = f2bf(v.y); o.z = f2bf(v.z); o.w = f2bf(v.w);
    reinterpret_cast<ushort4*>(dst)[i] = o;
}

// ---------------- 128x128 bf16 GEMM (out-proj): C = A * B^T ----------------
template<int OUT_BF16>
__global__ __launch_bounds__(256) void gemm_bt(
    const unsigned short* __restrict__ A,
    const unsigned short* __restrict__ B,
    void* __restrict__ C, int M, int N, int K) {
    __shared__ unsigned short As[128 * 32];
    __shared__ unsigned short Bs[128 * 32];
    const int tid = threadIdx.x;
    const int lane = tid & 63, wid = tid >> 6;
    const int wr = wid >> 1, wc = wid & 1;
    const int ln15 = lane & 15, kq = lane >> 4;
    const int bm = blockIdx.y, bn = blockIdx.x;

    f32x4 acc[4][4] = {};
    const int nk = K >> 5;
    for (int kt = 0; kt < nk; ++kt) {
        #pragma unroll
        for (int i = 0; i < 2; ++i) {
            int c = i * 256 + tid;
            int row = c >> 2, k8 = (c & 3) << 3;
            size_t gofsA = (size_t)(bm * 128 + row) * K + kt * 32 + k8;
            size_t gofsB = (size_t)(bn * 128 + row) * K + kt * 32 + k8;
            unsigned ldsoff = (unsigned)(i * 256 + wid * 64) * 16;  // wave-uniform
            gload_lds16(A + gofsA, (char*)As + ldsoff);
            gload_lds16(B + gofsB, (char*)Bs + ldsoff);
        }
        __syncthreads();
        bf16x8 af[4], bf[4];
        #pragma unroll
        for (int m = 0; m < 4; ++m)
            af[m] = *reinterpret_cast<const bf16x8*>(&As[(wr * 64 + m * 16 + ln15) * 32 + kq * 8]);
        #pragma unroll
        for (int n = 0; n < 4; ++n)
            bf[n] = *reinterpret_cast<const bf16x8*>(&Bs[(wc * 64 + n * 16 + ln15) * 32 + kq * 8]);
        #pragma unroll
        for (int m = 0; m < 4; ++m)
            #pragma unroll
            for (int n = 0; n < 4; ++n)
                acc[m][n] = __builtin_amdgcn_mfma_f32_16x16x32_bf16(af[m], bf[n], acc[m][n], 0, 0, 0);
        __syncthreads();
    }
    #pragma unroll
    for (int m = 0; m < 4; ++m) {
        #pragma unroll
        for (int n = 0; n < 4; ++n) {
            int col = bn * 128 + wc * 64 + n * 16 + ln15;
            #pragma unroll
            for (int j = 0; j < 4; ++j) {
                int row = bm * 128 + wr * 64 + m * 16 + kq * 4 + j;
                if constexpr (OUT_BF16 != 0)
                    ((unsigned short*)C)[(size_t)row * N + col] = f2bf(acc[m][n][j]);
                else
                    ((float*)C)[(size_t)row * N + col] = acc[m][n][j];
            }
        }
    }
}

// ---------------- 256x256 bf16 GEMM (qkv proj), 8-phase + fused epilogue -----
// 8 waves (2M x 4N), BK=64, 2 K-tiles per iteration, 8 phases (m201 schedule).
// Epilogue writes Qh/Kh with RoPE applied (pair (d,d^1) exchanged via
// __shfl_xor(1); cos/sin from tab) and Vtr transposed ([B,H,64,S], ushort4).
// bn>>2 selects Q/K/V -> block-uniform branch.
__global__ __launch_bounds__(512) void gemm256_bt(
    const unsigned short* __restrict__ A,
    const unsigned short* __restrict__ B,
    unsigned short* __restrict__ Qh, unsigned short* __restrict__ Kh,
    unsigned short* __restrict__ Vtr, const float2* __restrict__ tab, int K) {
    __shared__ unsigned short As[2][256 * 64];
    __shared__ unsigned short Bs[2][256 * 64];
    const int tid = threadIdx.x;
    const int lane = tid & 63, wid = tid >> 6;
    const int wm = wid >> 2, wn = wid & 3;          // 2 x 4 waves
    const int ln15 = lane & 15, g = lane >> 4;
    const int bm = blockIdx.y, bn = blockIdx.x;

    // staging sources: chunk c = tid + 512p; row = c>>3, slot = c&7 (16B units)
    const unsigned short* aSrc[4];
    const unsigned short* bSrc[4];
    #pragma unroll
    for (int p = 0; p < 4; ++p) {
        int c = tid + (p << 9);
        int row = c >> 3, slot = c & 7;
        aSrc[p] = A + (size_t)(bm * 256 + row) * K + ((slot ^ (row & 7)) << 3);
        bSrc[p] = B + (size_t)(bn * 256 + row) * K + ((slot ^ (row & 7)) << 3);
    }
    auto stageA = [&](int kt, int h) {   // one half-tile = 2 gload_lds / thread
        #pragma unroll
        for (int p = 2 * h; p < 2 * h + 2; ++p) {
            unsigned dst = (unsigned)(tid + (p << 9)) << 4;
            gload_lds16(aSrc[p] + kt * 64, (char*)As[kt & 1] + dst);
        }
    };
    auto stageB = [&](int kt, int h) {
        #pragma unroll
        for (int p = 2 * h; p < 2 * h + 2; ++p) {
            unsigned dst = (unsigned)(tid + (p << 9)) << 4;
            gload_lds16(bSrc[p] + kt * 64, (char*)Bs[kt & 1] + dst);
        }
    };

    const unsigned ps0 = (unsigned)((g ^ (ln15 & 7)) << 4);
    const unsigned ps1 = (unsigned)(((4 + g) ^ (ln15 & 7)) << 4);
    const unsigned aBase = (unsigned)(wm * 128 + ln15) * 128;
    const unsigned bBase = (unsigned)(wn * 64 + ln15) * 128;

    f32x4 acc[8][4] = {};
    const int nkt = K >> 6;          // 16 K-tiles
    const int nit = nkt >> 1;        // 8 iterations

    stageA(0, 0); stageA(0, 1);
    stageB(0, 0); stageB(0, 1);
    stageB(1, 0); stageB(1, 1);
    asm volatile("s_waitcnt vmcnt(0)" ::: "memory");
    __builtin_amdgcn_s_barrier();

    for (int j = 0; j < nit; ++j) {
        const int t0 = 2 * j, t1 = 2 * j + 1;
        const bool more = (t0 + 2) < nkt;
        #pragma unroll
        for (int grp = 0; grp < 2; ++grp) {          // grp0: tile t0 (buf0), grp1: t1 (buf1)
            const char* Ab = (const char*)As[grp];
            const char* Bb = (const char*)Bs[grp];
            bf16x8 bfr[4][2];
            #pragma unroll
            for (int q = 0; q < 4; ++q) {            // 4 phases per tile
                if (q == 0) {
                    #pragma unroll
                    for (int nf = 0; nf < 4; ++nf) {
                        bfr[nf][0] = *reinterpret_cast<const bf16x8*>(Bb + bBase + nf * 2048 + ps0);
                        bfr[nf][1] = *reinterpret_cast<const bf16x8*>(Bb + bBase + nf * 2048 + ps1);
                    }
                }
                bf16x8 af0 = *reinterpret_cast<const bf16x8*>(Ab + aBase + (2 * q) * 2048 + ps0);
                bf16x8 af1 = *reinterpret_cast<const bf16x8*>(Ab + aBase + (2 * q) * 2048 + ps1);
                bf16x8 af2 = *reinterpret_cast<const bf16x8*>(Ab + aBase + (2 * q + 1) * 2048 + ps0);
                bf16x8 af3 = *reinterpret_cast<const bf16x8*>(Ab + aBase + (2 * q + 1) * 2048 + ps1);

                if (grp == 0) {
                    if (q == 0) stageA(t1, 0);
                    else if (q == 1) stageA(t1, 1);
                    else if (q == 2) { if (more) stageB(t0 + 2, 0); }
                    else {
                        if (more) { stageB(t0 + 2, 1);
                                    asm volatile("s_waitcnt vmcnt(4)" ::: "memory"); }
                        else      { asm volatile("s_waitcnt vmcnt(0)" ::: "memory"); }
                    }
                } else {
                    if (q == 0)      { if (more) stageA(t0 + 2, 0); }
                    else if (q == 1) { if (more) stageA(t0 + 2, 1); }
                    else if (q == 2) { if (more) stageB(t1 + 2, 0); }
                    else {
                        if (more) { stageB(t1 + 2, 1);
                                    asm volatile("s_waitcnt vmcnt(4)" ::: "memory"); }
                        else      { asm volatile("s_waitcnt vmcnt(0)" ::: "memory"); }
                    }
                }

                __builtin_amdgcn_s_barrier();
                asm volatile("s_waitcnt lgkmcnt(0)" ::: "memory");
                __builtin_amdgcn_s_setprio(1);
                #pragma unroll
                for (int nf = 0; nf < 4; ++nf) {
                    acc[2 * q][nf] = __builtin_amdgcn_mfma_f32_16x16x32_bf16(af0, bfr[nf][0], acc[2 * q][nf], 0, 0, 0);
                    acc[2 * q][nf] = __builtin_amdgcn_mfma_f32_16x16x32_bf16(af1, bfr[nf][1], acc[2 * q][nf], 0, 0, 0);
                    acc[2 * q + 1][nf] = __builtin_amdgcn_mfma_f32_16x16x32_bf16(af2, bfr[nf][0], acc[2 * q + 1][nf], 0, 0, 0);
                    acc[2 * q + 1][nf] = __builtin_amdgcn_mfma_f32_16x16x32_bf16(af3, bfr[nf][1], acc[2 * q + 1][nf], 0, 0, 0);
                }
                __builtin_amdgcn_s_setprio(0);
                __builtin_amdgcn_s_barrier();
            }
        }
    }

    // ---- fused epilogue: RoPE for Q/K, transpose-store for V ----
    const int sel = bn >> 2;                          // 0=Q, 1=K, 2=V
    const int colBase = (bn & 3) * 256 + wn * 64;     // within 1024-wide section
    #pragma unroll
    for (int mf = 0; mf < 8; ++mf) {
        int row0 = bm * 256 + wm * 128 + mf * 16 + g * 4;
        int b = row0 >> 11, s0 = row0 & 2047;
        #pragma unroll
        for (int nf = 0; nf < 4; ++nf) {
            int col = colBase + nf * 16 + ln15;       // 0..1023
            int h = col >> 6, d = col & 63;
            if (sel == 2) {
                ushort4 w;
                w.x = f2bf(acc[mf][nf][0]); w.y = f2bf(acc[mf][nf][1]);
                w.z = f2bf(acc[mf][nf][2]); w.w = f2bf(acc[mf][nf][3]);
                *reinterpret_cast<ushort4*>(
                    &Vtr[(((size_t)(b * NH + h)) * 64 + d) * SEQ + s0]) = w;
            } else {
                unsigned short* dst = (sel == 0) ? Qh : Kh;
                const float sc = (sel == 0) ? QSCALE : 1.f;
                int i = d >> 1;
                #pragma unroll
                for (int j2 = 0; j2 < 4; ++j2) {
                    float v = acc[mf][nf][j2];
                    float p = __shfl_xor(v, 1);       // partner holds d^1
                    float2 cs = tab[((s0 + j2) << 5) + i];
                    float o = (d & 1) ? (v * cs.x + p * cs.y)
                                      : (v * cs.x - p * cs.y);
                    dst[(((size_t)(b * NH + h)) * SEQ + (s0 + j2)) * 64 + d] =
                        f2bf(o * sc);
                }
            }
        }
    }
}

// ---------------- RoPE cos/sin table: [S][32] float2 ----------------
__global__ __launch_bounds__(256) void rope_table(const int* __restrict__ pos,
                                                  float2* __restrict__ tab) {
    int idx = blockIdx.x * 256 + threadIdx.x;  // s*32 + i
    int s = idx >> 5, i = idx & 31;
    float fpos = (float)pos[s];
    float freq = exp2f(-(float)i * (13.287712379549449f / 32.0f));  // theta^(-i/32)
    float ang = fpos * freq, sn, cs;
    sincosf(ang, &sn, &cs);
    tab[idx] = make_float2(cs, sn);
}

// ---------------- causal flash attention, KVBLK=64, uniform band pairs --------
__global__ __launch_bounds__(128) void attn_kernel(
    const unsigned short* __restrict__ Qh, const unsigned short* __restrict__ Kh,
    const unsigned short* __restrict__ Vt, unsigned short* __restrict__ Out) {
    __shared__ unsigned short Kb[2][64 * 64];   // [k][d], chunk-swizzled rows
    __shared__ unsigned short Vb[2][64 * 64];   // [d][k], chunk-swizzled rows
    __shared__ unsigned short Plds[2][16 * 72]; // per-wave P

    const int tid = threadIdx.x;
    const int wid = tid >> 6, lane = tid & 63;
    const int ln15 = lane & 15, g = lane >> 4;
    const int bid = blockIdx.x;
    const int bh = bid & 31;
    const int pb = bid >> 5;                    // 0..31 -> bands {pb, 63-pb}

    const unsigned short* Qp = Qh + (size_t)bh * SEQ * 64;
    const unsigned short* Kp = Kh + (size_t)bh * SEQ * 64;
    const unsigned short* Vp = Vt + (size_t)bh * 64 * SEQ;
    char* Pc = (char*)Plds[wid];

    const unsigned short* kSrc[4];
    const unsigned short* vSrc[4];
    #pragma unroll
    for (int p = 0; p < 4; ++p) {
        int c = tid + (p << 7);
        int row = c >> 3, slot = c & 7;
        kSrc[p] = Kp + (size_t)row * 64 + ((slot ^ (row & 7)) << 3);
        vSrc[p] = Vp + (size_t)row * SEQ + ((slot ^ (row & 7)) << 3);
    }

    auto stage = [&](int kb, int buf) {   // 8 gload_lds per call
        #pragma unroll
        for (int p = 0; p < 4; ++p) {
            unsigned bb = (unsigned)(wid * 1024 + p * 2048);
            gload_lds16(kSrc[p] + (size_t)kb * 64, (char*)Kb[buf] + bb);
            gload_lds16(vSrc[p] + kb, (char*)Vb[buf] + bb);
        }
    };

    unsigned kOff[4][2], vOff[4][2];
    #pragma unroll
    for (int s = 0; s < 4; ++s) {
        int r = ln15 + 16 * s;
        kOff[s][0] = r * 128 + ((g ^ (r & 7)) << 4);
        kOff[s][1] = r * 128 + (((4 + g) ^ (r & 7)) << 4);
    }
    #pragma unroll
    for (int c = 0; c < 4; ++c) {
        int d = c * 16 + ln15;
        vOff[c][0] = d * 128 + ((g ^ (d & 7)) << 4);
        vOff[c][1] = d * 128 + (((4 + g) ^ (d & 7)) << 4);
    }
    const unsigned pW = (unsigned)(ln15 * 144 + 8 * g);   // + 32*s for quarter s
    const unsigned pR = (unsigned)(ln15 * 144 + 16 * g);  // + 64*h for half h

    const int b = bh >> 4, h = bh & 15;

    for (int bi = 0; bi < 2; ++bi) {
        const int bnd = bi ? (63 - pb) : pb;
        const int qb = bnd * 32 + wid * 16;
        const int nt = (bnd + 2) >> 1;          // 64-wide k-tiles
        const int thr = qb + ln15 - 4 * g;      // allowed: kb + 16s + 4g + j <= qb + ln15

        bf16x8 aq0 = *reinterpret_cast<const bf16x8*>(Qp + (size_t)(qb + ln15) * 64 + g * 8);
        bf16x8 aq1 = *reinterpret_cast<const bf16x8*>(Qp + (size_t)(qb + ln15) * 64 + 32 + g * 8);

        f32x4 oacc[4] = {};
        float lsum = 0.f;

        stage(0, 0);   // band prologue

        for (int t = 0; t < nt; ++t) {
            const int kb = t << 6;
            const int cur = t & 1;
            if (t + 1 < nt) {
                stage((t + 1) << 6, cur ^ 1);
                asm volatile("s_waitcnt vmcnt(8)" ::: "memory");  // tile t's 8 done
            } else {
                asm volatile("s_waitcnt vmcnt(0)" ::: "memory");
            }
            __builtin_amdgcn_s_barrier();

            const char* K0 = (const char*)Kb[cur];
            const char* V0 = (const char*)Vb[cur];
            bf16x8 kf[8], bv[8];
            #pragma unroll
            for (int s = 0; s < 4; ++s) {
                kf[2 * s]     = *reinterpret_cast<const bf16x8*>(K0 + kOff[s][0]);
                kf[2 * s + 1] = *reinterpret_cast<const bf16x8*>(K0 + kOff[s][1]);
            }
            #pragma unroll
            for (int c = 0; c < 4; ++c) {
                bv[2 * c]     = *reinterpret_cast<const bf16x8*>(V0 + vOff[c][0]);
                bv[2 * c + 1] = *reinterpret_cast<const bf16x8*>(V0 + vOff[c][1]);
            }

            const f32x4 z = {};
            f32x4 sq[4];
            #pragma unroll
            for (int s = 0; s < 4; ++s) {
                sq[s] = __builtin_amdgcn_mfma_f32_16x16x32_bf16(kf[2 * s], aq0, z, 0, 0, 0);
                sq[s] = __builtin_amdgcn_mfma_f32_16x16x32_bf16(kf[2 * s + 1], aq1, sq[s], 0, 0, 0);
            }

            float pv[4][4];
            if (t == nt - 1) {      // boundary tile: causal mask
                #pragma unroll
                for (int s = 0; s < 4; ++s)
                    #pragma unroll
                    for (int j = 0; j < 4; ++j)
                        pv[s][j] = (j <= thr - kb - 16 * s) ? EXP2(sq[s][j]) : 0.f;
            } else {
                #pragma unroll
                for (int s = 0; s < 4; ++s)
                    #pragma unroll
                    for (int j = 0; j < 4; ++j)
                        pv[s][j] = EXP2(sq[s][j]);
            }
            #pragma unroll
            for (int s = 0; s < 4; ++s)
                lsum += (pv[s][0] + pv[s][1]) + (pv[s][2] + pv[s][3]);

            #pragma unroll
            for (int s = 0; s < 4; ++s) {
                ushort4 w;
                w.x = f2bf(pv[s][0]); w.y = f2bf(pv[s][1]);
                w.z = f2bf(pv[s][2]); w.w = f2bf(pv[s][3]);
                *reinterpret_cast<ushort4*>(Pc + pW + 32 * s) = w;
            }
            asm volatile("s_waitcnt lgkmcnt(0)" ::: "memory");
            bf16x8 ap0 = *reinterpret_cast<const bf16x8*>(Pc + pR);
            bf16x8 ap1 = *reinterpret_cast<const bf16x8*>(Pc + pR + 64);
            #pragma unroll
            for (int c = 0; c < 4; ++c) {
                oacc[c] = __builtin_amdgcn_mfma_f32_16x16x32_bf16(ap0, bv[2 * c], oacc[c], 0, 0, 0);
                oacc[c] = __builtin_amdgcn_mfma_f32_16x16x32_bf16(ap1, bv[2 * c + 1], oacc[c], 0, 0, 0);
            }
            asm volatile("s_waitcnt lgkmcnt(0)" ::: "memory");  // buf[cur] reads done
            __builtin_amdgcn_s_barrier();
        }

        // normalize + store this band
        float r = lsum;
        r += __shfl_xor(r, 16);
        r += __shfl_xor(r, 32);
        float linv = 1.f / r;
        float invj[4];
        #pragma unroll
        for (int j = 0; j < 4; ++j)
            invj[j] = __shfl(linv, 20 * g + j);   // lane with ln15 == 4g+j
        #pragma unroll
        for (int c = 0; c < 4; ++c)
            #pragma unroll
            for (int j = 0; j < 4; ++j) {
                int s = qb + g * 4 + j;
                Out[((size_t)(b * SEQ + s)) * DM + h * 64 + c * 16 + ln15] =
                    f2bf(oacc[c][j] * invj[j]);
            }
    }
}

extern "C" void kernel_launch(void* const* d_in, const int* in_sizes, int n_in,
                              void* d_out, int out_size, void* d_ws, size_t ws_size,
                              hipStream_t stream) {
    const float* x = (const float*)d_in[0];
    const int* pos = (const int*)d_in[1];
    const float* Wq = (const float*)d_in[2];
    const float* Wk = (const float*)d_in[3];
    const float* Wv = (const float*)d_in[4];
    const float* Wo = (const float*)d_in[5];
    float* out = (float*)d_out;

    char* ws = (char*)d_ws;
    const size_t MB = 1024 * 1024;
    unsigned short* xb   = (unsigned short*)(ws + 0 * MB);
    unsigned short* wqkv = (unsigned short*)(ws + 8 * MB);   // wq|wk|wv contiguous
    unsigned short* wob  = (unsigned short*)(ws + 14 * MB);
    float2*         tab  = (float2*)       (ws + 40 * MB);   // [2048][32]
    unsigned short* qh   = (unsigned short*)(ws + 41 * MB);
    unsigned short* kh   = (unsigned short*)(ws + 49 * MB);
    unsigned short* vtr  = (unsigned short*)(ws + 57 * MB);
    unsigned short* att  = (unsigned short*)(ws + 65 * MB);

    cvt_all<<<8192, 256, 0, stream>>>(x, Wq, Wk, Wv, Wo, xb, wqkv, wob);
    rope_table<<<256, 256, 0, stream>>>(pos, tab);

    gemm256_bt<<<dim3(12, 16), 512, 0, stream>>>(xb, wqkv, qh, kh, vtr, tab, 1024);

    attn_kernel<<<1024, 128, 0, stream>>>(qh, kh, vtr, att);

    gemm_bt<0><<<dim3(8, 32), 256, 0, stream>>>(att, wob, out, 4096, 1024, 1024);
}